// Round 9
// baseline (4093.214 us; speedup 1.0000x reference)
//
#include <hip/hip_runtime.h>
#include <stdint.h>

// GNNCell: 2x SAGEConv(lstm) + 2 MLP heads. N=100000, D=16, H=128, fp32 I/O.
// R14/15 passed 2911 us (lstm 2x~1137, WRITE 72MB no spill; perm pack OK).
//     VALU 39.6 > MFMA 25.4 > HBM 14.5; occ 2 waves/SIMD (128 weight regs,
//     structural). Cycle model: ~35% all-wave stall, X gather latency
//     (600-900cy) vs ~240cy cover before first consume.
// R16: (1) X prefetch ONE STEP ahead: same 48 regs, refilled after last use
//     (post-ACT3, pre-pack) -> issue->use ~1500cy. nbrs pad col 16 zeroed
//     so T=15 dummy prefetch is in-bounds. Peak live set unchanged.
//     (2) exp2-domain: Wih/Whh/bias pre-scaled by log2e (gate g by 2log2e)
//     -> sigmoid/tanh = rcp(1+exp2(+-y)), no per-eval mul (only tanh(c)
//     keeps one). ~64 fewer VALU ops/step/lane. Outputs unscaled.
// Spill tripwire: WRITE_SIZE must stay ~72MB (R10/R13 lesson).
// Precision: X fp16-hi + i8-lo(2^-15) in scaled domain (relative grid
// unchanged); recurrence split-bf16 3-MFMA; heads bf16.

typedef __attribute__((ext_vector_type(8))) short short8_t;
typedef __attribute__((ext_vector_type(4))) float float4_t;
typedef __attribute__((ext_vector_type(4))) unsigned uint4_t;
typedef _Float16 half8_t __attribute__((ext_vector_type(8)));

#define NNODES 100000
#define DNB 16
#define LOSCALE 32768.0f
#define LOINV   3.0517578125e-5f   // 2^-15
#define L2E     1.4426950408889634f
#define TWOL2E  2.8853900817779268f

#if __has_builtin(__builtin_amdgcn_exp2f)
#define EXP2(x) __builtin_amdgcn_exp2f(x)
#else
#define EXP2(x) __expf((x) * 0.6931471805599453f)
#endif

// sigmoid(x) given y = x*log2e
__device__ __forceinline__ float fsig2(float y) {
    return __builtin_amdgcn_rcpf(1.f + EXP2(-y));
}
// tanh(x) given y = 2x*log2e
__device__ __forceinline__ float ftanh2(float y) {
    return 1.f - 2.f * __builtin_amdgcn_rcpf(1.f + EXP2(y));
}
__device__ __forceinline__ unsigned f2b(float f) {  // RNE f32->bf16 (finite)
    unsigned u = __float_as_uint(f);
    return (u + 0x7FFFu + ((u >> 16) & 1u)) >> 16;
}
__device__ __forceinline__ float blo(unsigned u) { return __uint_as_float(u << 16); }
__device__ __forceinline__ float bhi(unsigned u) { return __uint_as_float(u & 0xFFFF0000u); }
// pack hi16(u0) | hi16(u1)<<16 in ONE v_perm_b32 (builtin -> no reg pinning)
__device__ __forceinline__ unsigned pkhi(unsigned u0, unsigned u1) {
    return __builtin_amdgcn_perm(u1, u0, 0x07060302u);
}
// f2b-based split: compiler-friendly (values can migrate to AGPRs).
__device__ __forceinline__ void splitf8(const float* __restrict__ p, short8_t& hi, short8_t& lo) {
    float4_t a = *(const float4_t*)p;
    float4_t b = *(const float4_t*)(p + 4);
#pragma unroll
    for (int j = 0; j < 8; ++j) {
        float x = j < 4 ? a[j] : b[j - 4];
        unsigned hb = f2b(x);
        float hf = __uint_as_float(hb << 16);
        unsigned lb = f2b(x - hf);
        hi[j] = (short)hb;
        lo[j] = (short)lb;
    }
}
// scaled variant (for exp2-domain weights); f2b only, AGPR-friendly.
__device__ __forceinline__ void splitf8s(const float* __restrict__ p, float s,
                                         short8_t& hi, short8_t& lo) {
    float4_t a = *(const float4_t*)p;
    float4_t b = *(const float4_t*)(p + 4);
#pragma unroll
    for (int j = 0; j < 8; ++j) {
        float x = (j < 4 ? a[j] : b[j - 4]) * s;
        unsigned hb = f2b(x);
        float hf = __uint_as_float(hb << 16);
        unsigned lb = f2b(x - hf);
        hi[j] = (short)hb;
        lo[j] = (short)lb;
    }
}
// packed f32 pair -> 2x bf16 (inline asm: ONLY transient values in
// low-pressure kernels; never in lstm_comb).
__device__ __forceinline__ unsigned cvtpk(float lo, float hi) {
    unsigned r;
    asm("v_cvt_pk_bf16_f32 %0, %1, %2" : "=v"(r) : "v"(lo), "v"(hi));
    return r;
}
__device__ __forceinline__ void splitf8_pk(const float* __restrict__ p, short8_t& hi, short8_t& lo) {
    float4_t a = *(const float4_t*)p;
    float4_t b = *(const float4_t*)(p + 4);
    unsigned h0 = cvtpk(a[0], a[1]), h1 = cvtpk(a[2], a[3]);
    unsigned h2 = cvtpk(b[0], b[1]), h3 = cvtpk(b[2], b[3]);
    unsigned l0 = cvtpk(a[0] - blo(h0), a[1] - bhi(h0));
    unsigned l1 = cvtpk(a[2] - blo(h1), a[3] - bhi(h1));
    unsigned l2 = cvtpk(b[0] - blo(h2), b[1] - bhi(h2));
    unsigned l3 = cvtpk(b[2] - blo(h3), b[3] - bhi(h3));
    union { uint4_t u; short8_t s; } ch, cl;
    ch.u = (uint4_t){h0, h1, h2, h3};
    cl.u = (uint4_t){l0, l1, l2, l3};
    hi = ch.s;
    lo = cl.s;
}
// fp32[8] -> bf16x8 (plain cast, head path)
__device__ __forceinline__ short8_t cvtb8(const float* __restrict__ p) {
    float4_t a = *(const float4_t*)p;
    float4_t b = *(const float4_t*)(p + 4);
    union { uint4_t u; short8_t s; } c;
    c.u = (uint4_t){cvtpk(a[0], a[1]), cvtpk(a[2], a[3]),
                    cvtpk(b[0], b[1]), cvtpk(b[2], b[3])};
    return c.s;
}

// ---------------------------------------------------------------------------
// X = (h @ Wih.T + b) * gate_scale, split-bf16 3-MFMA, fp16-hi + i8-lo.
// gate_scale = log2e (gates i,f,o) or 2*log2e (gate g) -> exp2 domain.
// GATE-INTERLEAVED output: element c = g*128+j at node*512 + j*4 + g.
// ---------------------------------------------------------------------------
__global__ __launch_bounds__(256) void xgemm_split(
    const float* __restrict__ A, const float* __restrict__ B,
    const float* __restrict__ bias, _Float16* __restrict__ Chi,
    char* __restrict__ Clo)
{
    const int tid  = threadIdx.x;
    const int wave = tid >> 6, lane = tid & 63;
    const int l15  = lane & 15, quad = lane >> 4;
    const int r0   = blockIdx.y * 64 + wave * 16;
    const int c0   = blockIdx.x * 64;

    int arow = r0 + l15;
    if (arow >= NNODES) arow = NNODES - 1;

    float4_t acc[4];
#pragma unroll
    for (int ct = 0; ct < 4; ++ct) acc[ct] = (float4_t){0.f, 0.f, 0.f, 0.f};

#pragma unroll
    for (int kc = 0; kc < 4; ++kc) {
        const int kk = kc * 32 + quad * 8;
        short8_t ah, al;
        splitf8_pk(A + (size_t)arow * 128 + kk, ah, al);
#pragma unroll
        for (int ct = 0; ct < 4; ++ct) {
            short8_t bh, bl;
            splitf8_pk(B + (size_t)(c0 + ct * 16 + l15) * 128 + kk, bh, bl);
            acc[ct] = __builtin_amdgcn_mfma_f32_16x16x32_bf16(ah, bh, acc[ct], 0, 0, 0);
            acc[ct] = __builtin_amdgcn_mfma_f32_16x16x32_bf16(ah, bl, acc[ct], 0, 0, 0);
            acc[ct] = __builtin_amdgcn_mfma_f32_16x16x32_bf16(al, bh, acc[ct], 0, 0, 0);
        }
    }

#pragma unroll
    for (int ct = 0; ct < 4; ++ct) {
        int c = c0 + ct * 16 + l15;
        float bb = bias[c];
        const int jj = c & 127, gg = c >> 7;          // gate-interleaved slot
        const float sc = (((c0 + ct * 16) >> 7) == 2) ? TWOL2E : L2E;  // scalar/ct
#pragma unroll
        for (int r = 0; r < 4; ++r) {
            int rowo = r0 + quad * 4 + r;
            if (rowo < NNODES) {
                float v = (acc[ct][r] + bb) * sc;
                _Float16 hi = (_Float16)v;
                float res = v - (float)hi;
                int q = (int)rintf(res * LOSCALE);
                q = q > 127 ? 127 : (q < -127 ? -127 : q);
                Chi[(size_t)rowo * 512 + jj * 4 + gg] = hi;
                Clo[(size_t)rowo * 512 + jj * 4 + gg] = (char)q;
            }
        }
    }
}

// ---------------------------------------------------------------------------
// Fused 16-step LSTM + combine — R12/R9 structure (proven no-spill).
// Block = 64 nodes, 512 threads (8 waves); wave owns j-slice [16w,16w+16)
// for all 4 gates. hs double-buffered bf16 hi/lo LDS planes, 1 barrier/step.
// X gathers PREFETCHED ONE STEP AHEAD (same 48 regs, refilled post-ACT3,
// pre-pack; nbrs pad col 16 = 0 keeps T=15 dummy prefetch in-bounds).
// Whh pre-scaled to exp2 domain (gate g by 2log2e). nbr staged in LDS.
// hs re-pack: truncation split + v_perm packing (12 ops/nt, builtin only).
// ---------------------------------------------------------------------------
__global__ __launch_bounds__(512, 2) void lstm_comb(
    const _Float16* __restrict__ Xhi, const char* __restrict__ Xlo,
    const int* __restrict__ nbr, const float* __restrict__ Whh,
    const float* hin, const float* __restrict__ Ws,
    const float* __restrict__ Wn, const float* __restrict__ bs,
    const float* __restrict__ bn, float* hout)
{
    __shared__ short hsAhi[64 * 136], hsAlo[64 * 136];
    __shared__ short hsBhi[64 * 136], hsBlo[64 * 136];
    __shared__ int   nbrs[64 * 17];

    const int tid  = threadIdx.x;
    const int wave = tid >> 6, lane = tid & 63;
    const int l15  = lane & 15, quad = lane >> 4;
    const int n0   = blockIdx.x * 64;
    const int jb   = wave * 16;
    const int xoff = jb * 4 + quad * 16;   // gate-interleaved lane offset

    for (int i = tid; i < 64 * 136 / 2; i += 512) {
        ((unsigned*)hsAhi)[i] = 0;
        ((unsigned*)hsAlo)[i] = 0;
    }
    for (int i = tid; i < 64 * DNB; i += 512) {
        int node = n0 + (i >> 4);
        if (node >= NNODES) node = NNODES - 1;
        nbrs[(i >> 4) * 17 + (i & 15)] = nbr[node * DNB + (i & 15)];
    }
    if (tid < 64) nbrs[tid * 17 + 16] = 0;   // pad col: safe dummy for T=15 prefetch

    // Whh split fragments, exp2-domain scaled: 4 gates x 4 kc x (hi,lo)
    short8_t whi[4][4], wlo[4][4];
#pragma unroll
    for (int g = 0; g < 4; ++g) {
        const float sg = (g == 2) ? TWOL2E : L2E;
#pragma unroll
        for (int kc = 0; kc < 4; ++kc)
            splitf8s(Whh + (size_t)(g * 128 + jb + l15) * 128 + kc * 32 + quad * 8,
                     sg, whi[g][kc], wlo[g][kc]);
    }

    float cs[4][4], nh[4][4];
#pragma unroll
    for (int a = 0; a < 4; ++a)
#pragma unroll
        for (int b = 0; b < 4; ++b) { cs[a][b] = 0.f; nh[a][b] = 0.f; }

    __syncthreads();

    // X prefetch buffers: persist across steps (refilled after last use)
    half8_t xh0[4], xh1[4];
    uint4_t xl4[4];

// hi value (g,r) lives at vector slot r*4+g; lo byte g of word r.
#define XV(nt, r, g)                                                                \
    ((float)(((r) * 4 + (g)) < 8 ? xh0[nt][(r) * 4 + (g)] : xh1[nt][(r) * 4 + (g) - 8]) \
     + (float)((signed char)(xl4[nt][(r)] >> ((g) * 8))) * LOINV)

#define XLOADALL(T)                                                                 \
    {                                                                               \
        _Pragma("unroll")                                                           \
        for (int nt = 0; nt < 4; ++nt) {                                            \
            int gi = nbrs[(nt * 16 + l15) * 17 + (T)];                              \
            size_t xb = (size_t)gi * 512 + xoff;                                    \
            xh0[nt] = *(const half8_t*)(Xhi + xb);                                  \
            xh1[nt] = *(const half8_t*)(Xhi + xb + 8);                              \
            xl4[nt] = *(const uint4_t*)(Xlo + xb);                                  \
        }                                                                           \
    }

#define LSTM_STEP(rdHi, rdLo, wrHi, wrLo, T)                                        \
    {                                                                               \
        _Pragma("unroll")                                                           \
        for (int nt = 0; nt < 4; ++nt) {                                            \
            short8_t hfh[4], hfl[4];                                                \
            _Pragma("unroll")                                                       \
            for (int kc = 0; kc < 4; ++kc) {                                        \
                hfh[kc] = *(const short8_t*)&(rdHi)[(nt * 16 + l15) * 136 + kc * 32 + quad * 8]; \
                hfl[kc] = *(const short8_t*)&(rdLo)[(nt * 16 + l15) * 136 + kc * 32 + quad * 8]; \
            }                                                                       \
            float4_t ac[4];                                                         \
            _Pragma("unroll")                                                       \
            for (int g = 0; g < 4; ++g) {                                           \
                float4_t a = (float4_t){0.f, 0.f, 0.f, 0.f};                        \
                _Pragma("unroll")                                                   \
                for (int kc = 0; kc < 4; ++kc) {                                    \
                    a = __builtin_amdgcn_mfma_f32_16x16x32_bf16(whi[g][kc], hfh[kc], a, 0, 0, 0); \
                    a = __builtin_amdgcn_mfma_f32_16x16x32_bf16(whi[g][kc], hfl[kc], a, 0, 0, 0); \
                    a = __builtin_amdgcn_mfma_f32_16x16x32_bf16(wlo[g][kc], hfh[kc], a, 0, 0, 0); \
                }                                                                   \
                ac[g] = a;                                                          \
            }                                                                       \
            _Pragma("unroll")                                                       \
            for (int r = 0; r < 4; ++r) {                                           \
                float iv = ac[0][r] + XV(nt, r, 0);                                 \
                float fv = ac[1][r] + XV(nt, r, 1);                                 \
                float gv = ac[2][r] + XV(nt, r, 2);                                 \
                float ov = ac[3][r] + XV(nt, r, 3);                                 \
                float c = fsig2(fv) * cs[nt][r] + fsig2(iv) * ftanh2(gv);           \
                cs[nt][r] = c;                                                      \
                nh[nt][r] = fsig2(ov) * ftanh2(c * TWOL2E);                         \
            }                                                                       \
        }                                                                           \
        XLOADALL((T) + 1)                                                           \
        _Pragma("unroll")                                                           \
        for (int nt = 0; nt < 4; ++nt) {                                            \
            unsigned u0 = __float_as_uint(nh[nt][0]);                               \
            unsigned u1 = __float_as_uint(nh[nt][1]);                               \
            unsigned u2 = __float_as_uint(nh[nt][2]);                               \
            unsigned u3 = __float_as_uint(nh[nt][3]);                               \
            unsigned r0 = __float_as_uint(nh[nt][0] - bhi(u0));                     \
            unsigned r1 = __float_as_uint(nh[nt][1] - bhi(u1));                     \
            unsigned r2 = __float_as_uint(nh[nt][2] - bhi(u2));                     \
            unsigned r3 = __float_as_uint(nh[nt][3] - bhi(u3));                     \
            uint2 ph, pl;                                                           \
            ph.x = pkhi(u0, u1); ph.y = pkhi(u2, u3);                               \
            pl.x = pkhi(r0, r1); pl.y = pkhi(r2, r3);                               \
            const int o = (nt * 16 + l15) * 136 + jb + quad * 4;                    \
            *(uint2*)&(wrHi)[o] = ph;                                               \
            *(uint2*)&(wrLo)[o] = pl;                                               \
        }                                                                           \
        __syncthreads();                                                            \
    }

    XLOADALL(0)   // prologue: step-0 gathers in flight before first GEMM

    for (int tp = 0; tp < 8; ++tp) {
        LSTM_STEP(hsAhi, hsAlo, hsBhi, hsBlo, 2 * tp);      // even t: read A write B
        LSTM_STEP(hsBhi, hsBlo, hsAhi, hsAlo, 2 * tp + 1);  // odd  t: read B write A
    }
#undef LSTM_STEP
#undef XLOADALL
#undef XV
    // t=15 (odd) wrote A planes -> h_neigh lives in hsA.

    // ---- fused combine: h' = relu(hin@Ws.T + hn@Wn.T + bs + bn) ----
    const int ng = wave & 3, ch = wave >> 2;
    const int nodeA = n0 + ng * 16 + l15;
    const int nclA  = nodeA < NNODES ? nodeA : NNODES - 1;
    short8_t ahh[4], ahl[4], anh[4], anl[4];
#pragma unroll
    for (int kc = 0; kc < 4; ++kc) {
        splitf8(hin + (size_t)nclA * 128 + kc * 32 + quad * 8, ahh[kc], ahl[kc]);
        anh[kc] = *(const short8_t*)&hsAhi[(ng * 16 + l15) * 136 + kc * 32 + quad * 8];
        anl[kc] = *(const short8_t*)&hsAlo[(ng * 16 + l15) * 136 + kc * 32 + quad * 8];
    }
    __syncthreads();   // all hin reads done before any in-place store

#pragma unroll
    for (int ct = 0; ct < 4; ++ct) {
        const int ctg = ch * 4 + ct;
        float4_t acc = (float4_t){0.f, 0.f, 0.f, 0.f};
#pragma unroll
        for (int kc = 0; kc < 4; ++kc) {
            const int kk = kc * 32 + quad * 8;
            short8_t bh, bl;
            splitf8(Ws + (size_t)(ctg * 16 + l15) * 128 + kk, bh, bl);
            acc = __builtin_amdgcn_mfma_f32_16x16x32_bf16(ahh[kc], bh, acc, 0, 0, 0);
            acc = __builtin_amdgcn_mfma_f32_16x16x32_bf16(ahh[kc], bl, acc, 0, 0, 0);
            acc = __builtin_amdgcn_mfma_f32_16x16x32_bf16(ahl[kc], bh, acc, 0, 0, 0);
            splitf8(Wn + (size_t)(ctg * 16 + l15) * 128 + kk, bh, bl);
            acc = __builtin_amdgcn_mfma_f32_16x16x32_bf16(anh[kc], bh, acc, 0, 0, 0);
            acc = __builtin_amdgcn_mfma_f32_16x16x32_bf16(anh[kc], bl, acc, 0, 0, 0);
            acc = __builtin_amdgcn_mfma_f32_16x16x32_bf16(anl[kc], bh, acc, 0, 0, 0);
        }
        const int c = ctg * 16 + l15;
        const float bb = bs[c] + bn[c];
#pragma unroll
        for (int r = 0; r < 4; ++r) {
            int rowo = n0 + ng * 16 + quad * 4 + r;
            if (rowo < NNODES) {
                float v = acc[r] + bb;
                hout[(size_t)rowo * 128 + c] = v > 0.f ? v : 0.f;
            }
        }
    }
}

// ---------------------------------------------------------------------------
// Fused MLP heads (unchanged from R12).
// ---------------------------------------------------------------------------
__global__ __launch_bounds__(256) void heads_fused(
    const float* __restrict__ hsrc,
    const float* __restrict__ clsW, const float* __restrict__ clsb,
    const float* __restrict__ clsoW, const float* __restrict__ clsob,
    const float* __restrict__ cnfW, const float* __restrict__ cnfb,
    const float* __restrict__ cnfoW, const float* __restrict__ cnfob,
    float* __restrict__ oC, float* __restrict__ oL)
{
    __shared__ short xb[64 * 132];    // activations (bf16)
    __shared__ short wb[128 * 132];   // current layer weights (bf16)

    const int tid  = threadIdx.x;
    const int wave = tid >> 6, lane = tid & 63;
    const int l15  = lane & 15, quad = lane >> 4;
    const int n0   = blockIdx.x * 64;

    {
        int row = tid >> 2, cb = (tid & 3) * 32;
        int rsrc = n0 + row; if (rsrc >= NNODES) rsrc = NNODES - 1;
        const float* src = hsrc + (size_t)rsrc * 128 + cb;
#pragma unroll
        for (int i = 0; i < 4; ++i)
            *(short8_t*)&xb[row * 132 + cb + i * 8] = cvtb8(src + i * 8);
    }

    for (int head = 0; head < 2; ++head) {
        const float* W  = head ? cnfW : clsW;
        const float* bv = head ? cnfb : clsb;

        if (head == 1) {
            __syncthreads();
            int row = tid >> 2, cb = (tid & 3) * 32;
            int rsrc = n0 + row; if (rsrc >= NNODES) rsrc = NNODES - 1;
            const float* src = hsrc + (size_t)rsrc * 128 + cb;
#pragma unroll
            for (int i = 0; i < 4; ++i)
                *(short8_t*)&xb[row * 132 + cb + i * 8] = cvtb8(src + i * 8);
        }

        for (int l = 0; l < 5; ++l) {
            __syncthreads();
            short8_t af[4];
#pragma unroll
            for (int kc = 0; kc < 4; ++kc)
                af[kc] = *(const short8_t*)&xb[(wave * 16 + l15) * 132 + kc * 32 + quad * 8];
            const float* Wl = W + (size_t)l * 16384;
#pragma unroll
            for (int i = 0; i < 8; ++i) {
                int e = i * 2048 + tid * 8;
                int r = e >> 7, c = e & 127;
                *(short8_t*)&wb[r * 132 + c] = cvtb8(Wl + e);
            }
            __syncthreads();
#pragma unroll
            for (int ct = 0; ct < 8; ++ct) {
                float4_t acc = (float4_t){0.f, 0.f, 0.f, 0.f};
#pragma unroll
                for (int kc = 0; kc < 4; ++kc) {
                    short8_t bf = *(const short8_t*)&wb[(ct * 16 + l15) * 132 + kc * 32 + quad * 8];
                    acc = __builtin_amdgcn_mfma_f32_16x16x32_bf16(af[kc], bf, acc, 0, 0, 0);
                }
                int c = ct * 16 + l15;
                float bb = bv[l * 128 + c];
#pragma unroll
                for (int r = 0; r < 4; ++r) {
                    float v = acc[r] + bb;
                    v = v > 0.f ? v : 0.f;
                    xb[(wave * 16 + quad * 4 + r) * 132 + c] = (short)f2b(v);
                }
            }
        }

        __syncthreads();
        short8_t af[4];
#pragma unroll
        for (int kc = 0; kc < 4; ++kc)
            af[kc] = *(const short8_t*)&xb[(wave * 16 + l15) * 132 + kc * 32 + quad * 8];
        if (head == 0) {
            int wr = l15 < 10 ? l15 : 9;
            float4_t acc = (float4_t){0.f, 0.f, 0.f, 0.f};
#pragma unroll
            for (int kc = 0; kc < 4; ++kc) {
                short8_t bh, bl;
                splitf8(clsoW + (size_t)wr * 128 + kc * 32 + quad * 8, bh, bl);
                acc = __builtin_amdgcn_mfma_f32_16x16x32_bf16(af[kc], bh, acc, 0, 0, 0);
                acc = __builtin_amdgcn_mfma_f32_16x16x32_bf16(af[kc], bl, acc, 0, 0, 0);
            }
            if (l15 < 10) {
                float bb = clsob[l15];
#pragma unroll
                for (int r = 0; r < 4; ++r) {
                    int row = n0 + wave * 16 + quad * 4 + r;
                    if (row < NNODES) oC[(size_t)row * 10 + l15] = acc[r] + bb;
                }
            }
        } else {
            float4_t acc = (float4_t){0.f, 0.f, 0.f, 0.f};
#pragma unroll
            for (int kc = 0; kc < 4; ++kc) {
                short8_t bh, bl;
                splitf8(cnfoW + kc * 32 + quad * 8, bh, bl);
                acc = __builtin_amdgcn_mfma_f32_16x16x32_bf16(af[kc], bh, acc, 0, 0, 0);
                acc = __builtin_amdgcn_mfma_f32_16x16x32_bf16(af[kc], bl, acc, 0, 0, 0);
            }
            if (l15 == 0) {
                float bb = cnfob[0];
#pragma unroll
                for (int r = 0; r < 4; ++r) {
                    int row = n0 + wave * 16 + quad * 4 + r;
                    if (row < NNODES) oL[row] = acc[r] + bb;
                }
            }
        }
    }
}

// ===========================================================================
extern "C" void kernel_launch(void* const* d_in, const int* in_sizes, int n_in,
                              void* d_out, int out_size, void* d_ws, size_t ws_size,
                              hipStream_t stream)
{
    const float* h0     = (const float*)d_in[0];
    const int*   nbr    = (const int*)d_in[1];
    const float* Wih    = (const float*)d_in[2];   // [2,512,128]
    const float* Whh    = (const float*)d_in[3];   // [2,512,128]
    const float* lb     = (const float*)d_in[4];   // [2,512]
    const float* Wself  = (const float*)d_in[5];   // [2,128,128]
    const float* bself  = (const float*)d_in[6];
    const float* Wneigh = (const float*)d_in[7];
    const float* bneigh = (const float*)d_in[8];
    const float* clsW   = (const float*)d_in[9];   // [5,128,128]
    const float* clsb   = (const float*)d_in[10];
    const float* clsoW  = (const float*)d_in[11];  // [10,128]
    const float* clsob  = (const float*)d_in[12];
    const float* cnfW   = (const float*)d_in[13];
    const float* cnfb   = (const float*)d_in[14];
    const float* cnfoW  = (const float*)d_in[15];  // [1,128]
    const float* cnfob  = (const float*)d_in[16];

    char* ws = (char*)d_ws;
    _Float16* Xhi = (_Float16*)ws;                 // [0, 102.4M)
    char*     Xlo = ws + 102400000;                // [102.4M, 153.6M)

    float* out = (float*)d_out;
    float* oC  = out;                   // [N,10]
    float* hO  = out + 1000000;         // [N,128]; h1/h2 live here
    float* oL  = out + 13800000;        // [N,1]

    dim3 gx(8, 1563);    // xgemm: cols fast, M=100000, NC=512
    dim3 gl(1563);       // lstm, 512 thr
    dim3 gf(1563);       // heads_fused, 256 thr

    // ---- layer 1: h1 -> d_out h slot ----
    xgemm_split<<<gx, dim3(256), 0, stream>>>(h0, Wih, lb, Xhi, Xlo);
    lstm_comb<<<gl, dim3(512), 0, stream>>>(Xhi, Xlo, nbr, Whh, h0,
                                            Wself, Wneigh, bself, bneigh, hO);
    // ---- layer 2: h2 -> same slot, in-place ----
    xgemm_split<<<gx, dim3(256), 0, stream>>>(hO, Wih + 65536, lb + 512, Xhi, Xlo);
    lstm_comb<<<gl, dim3(512), 0, stream>>>(Xhi, Xlo, nbr, Whh + 65536, hO,
                                            Wself + 16384, Wneigh + 16384,
                                            bself + 128, bneigh + 128, hO);

    // ---- heads: one fused dispatch ----
    heads_fused<<<gf, dim3(256), 0, stream>>>(hO, clsW, clsb, clsoW, clsob,
                                              cnfW, cnfb, cnfoW, cnfob, oC, oL);
}

// Round 10
// 3064.893 us; speedup vs baseline: 1.3355x; 1.3355x over previous
//
#include <hip/hip_runtime.h>
#include <stdint.h>

// GNNCell: 2x SAGEConv(lstm) + 2 MLP heads. N=100000, D=16, H=128, fp32 I/O.
// R14/15 passed 2911 us (lstm 2x~1137, WRITE 72MB no spill).
// R16 REGRESSED 4093: cross-step X prefetch extended X live range across
//     pack+barrier -> spill (WRITE 1.14GB). Third confirmation: the lstm
//     structure has ZERO register headroom; only work-removal helps.
// R17: two changes that strictly SHRINK the live set:
//     (1) X = fp16 ONLY (drop i8-lo plane). R13 evidence: absmax is
//         insensitive to X precision (exact fp32 -> identical 0.00390625).
//         Unpack ~80->~20 ops/nt, loads 3->2 per nt, gather bytes -33%,
//         xl4 registers freed.
//     (2) exp2-domain (isolated from R16's spill): Wih/Whh/bias pre-scaled
//         by log2e (gate g by 2log2e); sigmoid/tanh = rcp(1+exp2(+-y)),
//         no per-eval mul (only tanh(c) keeps one). No live-state change.
// Structure otherwise byte-identical to R14 (proven no-spill).
// Spill tripwire: WRITE_SIZE must stay ~72MB.

typedef __attribute__((ext_vector_type(8))) short short8_t;
typedef __attribute__((ext_vector_type(4))) float float4_t;
typedef __attribute__((ext_vector_type(4))) unsigned uint4_t;
typedef _Float16 half8_t __attribute__((ext_vector_type(8)));

#define NNODES 100000
#define DNB 16
#define L2E     1.4426950408889634f
#define TWOL2E  2.8853900817779268f

#if __has_builtin(__builtin_amdgcn_exp2f)
#define EXP2(x) __builtin_amdgcn_exp2f(x)
#else
#define EXP2(x) __expf((x) * 0.6931471805599453f)
#endif

// sigmoid(x) given y = x*log2e
__device__ __forceinline__ float fsig2(float y) {
    return __builtin_amdgcn_rcpf(1.f + EXP2(-y));
}
// tanh(x) given y = 2x*log2e
__device__ __forceinline__ float ftanh2(float y) {
    return 1.f - 2.f * __builtin_amdgcn_rcpf(1.f + EXP2(y));
}
__device__ __forceinline__ unsigned f2b(float f) {  // RNE f32->bf16 (finite)
    unsigned u = __float_as_uint(f);
    return (u + 0x7FFFu + ((u >> 16) & 1u)) >> 16;
}
__device__ __forceinline__ float blo(unsigned u) { return __uint_as_float(u << 16); }
__device__ __forceinline__ float bhi(unsigned u) { return __uint_as_float(u & 0xFFFF0000u); }
// pack hi16(u0) | hi16(u1)<<16 in ONE v_perm_b32 (builtin -> no reg pinning)
__device__ __forceinline__ unsigned pkhi(unsigned u0, unsigned u1) {
    return __builtin_amdgcn_perm(u1, u0, 0x07060302u);
}
// f2b-based split: compiler-friendly (values can migrate to AGPRs).
__device__ __forceinline__ void splitf8(const float* __restrict__ p, short8_t& hi, short8_t& lo) {
    float4_t a = *(const float4_t*)p;
    float4_t b = *(const float4_t*)(p + 4);
#pragma unroll
    for (int j = 0; j < 8; ++j) {
        float x = j < 4 ? a[j] : b[j - 4];
        unsigned hb = f2b(x);
        float hf = __uint_as_float(hb << 16);
        unsigned lb = f2b(x - hf);
        hi[j] = (short)hb;
        lo[j] = (short)lb;
    }
}
// scaled variant (exp2-domain weights); f2b only, AGPR-friendly.
__device__ __forceinline__ void splitf8s(const float* __restrict__ p, float s,
                                         short8_t& hi, short8_t& lo) {
    float4_t a = *(const float4_t*)p;
    float4_t b = *(const float4_t*)(p + 4);
#pragma unroll
    for (int j = 0; j < 8; ++j) {
        float x = (j < 4 ? a[j] : b[j - 4]) * s;
        unsigned hb = f2b(x);
        float hf = __uint_as_float(hb << 16);
        unsigned lb = f2b(x - hf);
        hi[j] = (short)hb;
        lo[j] = (short)lb;
    }
}
// packed f32 pair -> 2x bf16 (inline asm: ONLY transient values in
// low-pressure kernels; never in lstm_comb).
__device__ __forceinline__ unsigned cvtpk(float lo, float hi) {
    unsigned r;
    asm("v_cvt_pk_bf16_f32 %0, %1, %2" : "=v"(r) : "v"(lo), "v"(hi));
    return r;
}
__device__ __forceinline__ void splitf8_pk(const float* __restrict__ p, short8_t& hi, short8_t& lo) {
    float4_t a = *(const float4_t*)p;
    float4_t b = *(const float4_t*)(p + 4);
    unsigned h0 = cvtpk(a[0], a[1]), h1 = cvtpk(a[2], a[3]);
    unsigned h2 = cvtpk(b[0], b[1]), h3 = cvtpk(b[2], b[3]);
    unsigned l0 = cvtpk(a[0] - blo(h0), a[1] - bhi(h0));
    unsigned l1 = cvtpk(a[2] - blo(h1), a[3] - bhi(h1));
    unsigned l2 = cvtpk(b[0] - blo(h2), b[1] - bhi(h2));
    unsigned l3 = cvtpk(b[2] - blo(h3), b[3] - bhi(h3));
    union { uint4_t u; short8_t s; } ch, cl;
    ch.u = (uint4_t){h0, h1, h2, h3};
    cl.u = (uint4_t){l0, l1, l2, l3};
    hi = ch.s;
    lo = cl.s;
}
// fp32[8] -> bf16x8 (plain cast, head path)
__device__ __forceinline__ short8_t cvtb8(const float* __restrict__ p) {
    float4_t a = *(const float4_t*)p;
    float4_t b = *(const float4_t*)(p + 4);
    union { uint4_t u; short8_t s; } c;
    c.u = (uint4_t){cvtpk(a[0], a[1]), cvtpk(a[2], a[3]),
                    cvtpk(b[0], b[1]), cvtpk(b[2], b[3])};
    return c.s;
}

// ---------------------------------------------------------------------------
// X = (h @ Wih.T + b) * gate_scale, split-bf16 3-MFMA, stored fp16 ONLY.
// gate_scale = log2e (gates i,f,o) or 2*log2e (gate g) -> exp2 domain.
// GATE-INTERLEAVED output: element c = g*128+j at node*512 + j*4 + g.
// ---------------------------------------------------------------------------
__global__ __launch_bounds__(256) void xgemm_h(
    const float* __restrict__ A, const float* __restrict__ B,
    const float* __restrict__ bias, _Float16* __restrict__ Chi)
{
    const int tid  = threadIdx.x;
    const int wave = tid >> 6, lane = tid & 63;
    const int l15  = lane & 15, quad = lane >> 4;
    const int r0   = blockIdx.y * 64 + wave * 16;
    const int c0   = blockIdx.x * 64;

    int arow = r0 + l15;
    if (arow >= NNODES) arow = NNODES - 1;

    float4_t acc[4];
#pragma unroll
    for (int ct = 0; ct < 4; ++ct) acc[ct] = (float4_t){0.f, 0.f, 0.f, 0.f};

#pragma unroll
    for (int kc = 0; kc < 4; ++kc) {
        const int kk = kc * 32 + quad * 8;
        short8_t ah, al;
        splitf8_pk(A + (size_t)arow * 128 + kk, ah, al);
#pragma unroll
        for (int ct = 0; ct < 4; ++ct) {
            short8_t bh, bl;
            splitf8_pk(B + (size_t)(c0 + ct * 16 + l15) * 128 + kk, bh, bl);
            acc[ct] = __builtin_amdgcn_mfma_f32_16x16x32_bf16(ah, bh, acc[ct], 0, 0, 0);
            acc[ct] = __builtin_amdgcn_mfma_f32_16x16x32_bf16(ah, bl, acc[ct], 0, 0, 0);
            acc[ct] = __builtin_amdgcn_mfma_f32_16x16x32_bf16(al, bh, acc[ct], 0, 0, 0);
        }
    }

#pragma unroll
    for (int ct = 0; ct < 4; ++ct) {
        int c = c0 + ct * 16 + l15;
        float bb = bias[c];
        const int jj = c & 127, gg = c >> 7;          // gate-interleaved slot
        const float sc = (((c0 + ct * 16) >> 7) == 2) ? TWOL2E : L2E;
#pragma unroll
        for (int r = 0; r < 4; ++r) {
            int rowo = r0 + quad * 4 + r;
            if (rowo < NNODES)
                Chi[(size_t)rowo * 512 + jj * 4 + gg] = (_Float16)((acc[ct][r] + bb) * sc);
        }
    }
}

// ---------------------------------------------------------------------------
// Fused 16-step LSTM + combine — R14 structure (proven no-spill).
// Block = 64 nodes, 512 threads (8 waves); wave owns j-slice [16w,16w+16)
// for all 4 gates. hs double-buffered bf16 hi/lo LDS planes, 1 barrier/step.
// X: fp16 only, 2x16B loads/lane/nt at step start, consumed post-GEMM.
// Whh pre-scaled to exp2 domain. nbr staged in LDS.
// hs re-pack: truncation split + v_perm packing (12 ops/nt, builtin only).
// ---------------------------------------------------------------------------
__global__ __launch_bounds__(512, 2) void lstm_comb(
    const _Float16* __restrict__ Xhi,
    const int* __restrict__ nbr, const float* __restrict__ Whh,
    const float* hin, const float* __restrict__ Ws,
    const float* __restrict__ Wn, const float* __restrict__ bs,
    const float* __restrict__ bn, float* hout)
{
    __shared__ short hsAhi[64 * 136], hsAlo[64 * 136];
    __shared__ short hsBhi[64 * 136], hsBlo[64 * 136];
    __shared__ int   nbrs[64 * 17];

    const int tid  = threadIdx.x;
    const int wave = tid >> 6, lane = tid & 63;
    const int l15  = lane & 15, quad = lane >> 4;
    const int n0   = blockIdx.x * 64;
    const int jb   = wave * 16;
    const int xoff = jb * 4 + quad * 16;   // gate-interleaved lane offset

    for (int i = tid; i < 64 * 136 / 2; i += 512) {
        ((unsigned*)hsAhi)[i] = 0;
        ((unsigned*)hsAlo)[i] = 0;
    }
    for (int i = tid; i < 64 * DNB; i += 512) {
        int node = n0 + (i >> 4);
        if (node >= NNODES) node = NNODES - 1;
        nbrs[(i >> 4) * 17 + (i & 15)] = nbr[node * DNB + (i & 15)];
    }

    // Whh split fragments, exp2-domain: 4 gates x 4 kc x (hi,lo) = 32 frags
    short8_t whi[4][4], wlo[4][4];
#pragma unroll
    for (int g = 0; g < 4; ++g) {
        const float sg = (g == 2) ? TWOL2E : L2E;
#pragma unroll
        for (int kc = 0; kc < 4; ++kc)
            splitf8s(Whh + (size_t)(g * 128 + jb + l15) * 128 + kc * 32 + quad * 8,
                     sg, whi[g][kc], wlo[g][kc]);
    }

    float cs[4][4], nh[4][4];
#pragma unroll
    for (int a = 0; a < 4; ++a)
#pragma unroll
        for (int b = 0; b < 4; ++b) { cs[a][b] = 0.f; nh[a][b] = 0.f; }

    __syncthreads();

// hi value (g,r) lives at vector slot r*4+g across xh0/xh1.
#define XV(nt, r, g)                                                                \
    ((float)(((r) * 4 + (g)) < 8 ? xh0[nt][(r) * 4 + (g)] : xh1[nt][(r) * 4 + (g) - 8]))

#define LSTM_STEP(rdHi, rdLo, wrHi, wrLo, T)                                        \
    {                                                                               \
        half8_t xh0[4], xh1[4];                                                     \
        _Pragma("unroll")                                                           \
        for (int nt = 0; nt < 4; ++nt) {                                            \
            int gi = nbrs[(nt * 16 + l15) * 17 + (T)];                              \
            size_t xb = (size_t)gi * 512 + xoff;                                    \
            xh0[nt] = *(const half8_t*)(Xhi + xb);                                  \
            xh1[nt] = *(const half8_t*)(Xhi + xb + 8);                              \
        }                                                                           \
        _Pragma("unroll")                                                           \
        for (int nt = 0; nt < 4; ++nt) {                                            \
            short8_t hfh[4], hfl[4];                                                \
            _Pragma("unroll")                                                       \
            for (int kc = 0; kc < 4; ++kc) {                                        \
                hfh[kc] = *(const short8_t*)&(rdHi)[(nt * 16 + l15) * 136 + kc * 32 + quad * 8]; \
                hfl[kc] = *(const short8_t*)&(rdLo)[(nt * 16 + l15) * 136 + kc * 32 + quad * 8]; \
            }                                                                       \
            float4_t ac[4];                                                         \
            _Pragma("unroll")                                                       \
            for (int g = 0; g < 4; ++g) {                                           \
                float4_t a = (float4_t){0.f, 0.f, 0.f, 0.f};                        \
                _Pragma("unroll")                                                   \
                for (int kc = 0; kc < 4; ++kc) {                                    \
                    a = __builtin_amdgcn_mfma_f32_16x16x32_bf16(whi[g][kc], hfh[kc], a, 0, 0, 0); \
                    a = __builtin_amdgcn_mfma_f32_16x16x32_bf16(whi[g][kc], hfl[kc], a, 0, 0, 0); \
                    a = __builtin_amdgcn_mfma_f32_16x16x32_bf16(wlo[g][kc], hfh[kc], a, 0, 0, 0); \
                }                                                                   \
                ac[g] = a;                                                          \
            }                                                                       \
            _Pragma("unroll")                                                       \
            for (int r = 0; r < 4; ++r) {                                           \
                float iv = ac[0][r] + XV(nt, r, 0);                                 \
                float fv = ac[1][r] + XV(nt, r, 1);                                 \
                float gv = ac[2][r] + XV(nt, r, 2);                                 \
                float ov = ac[3][r] + XV(nt, r, 3);                                 \
                float c = fsig2(fv) * cs[nt][r] + fsig2(iv) * ftanh2(gv);           \
                cs[nt][r] = c;                                                      \
                nh[nt][r] = fsig2(ov) * ftanh2(c * TWOL2E);                         \
            }                                                                       \
        }                                                                           \
        _Pragma("unroll")                                                           \
        for (int nt = 0; nt < 4; ++nt) {                                            \
            unsigned u0 = __float_as_uint(nh[nt][0]);                               \
            unsigned u1 = __float_as_uint(nh[nt][1]);                               \
            unsigned u2 = __float_as_uint(nh[nt][2]);                               \
            unsigned u3 = __float_as_uint(nh[nt][3]);                               \
            unsigned r0 = __float_as_uint(nh[nt][0] - bhi(u0));                     \
            unsigned r1 = __float_as_uint(nh[nt][1] - bhi(u1));                     \
            unsigned r2 = __float_as_uint(nh[nt][2] - bhi(u2));                     \
            unsigned r3 = __float_as_uint(nh[nt][3] - bhi(u3));                     \
            uint2 ph, pl;                                                           \
            ph.x = pkhi(u0, u1); ph.y = pkhi(u2, u3);                               \
            pl.x = pkhi(r0, r1); pl.y = pkhi(r2, r3);                               \
            const int o = (nt * 16 + l15) * 136 + jb + quad * 4;                    \
            *(uint2*)&(wrHi)[o] = ph;                                               \
            *(uint2*)&(wrLo)[o] = pl;                                               \
        }                                                                           \
        __syncthreads();                                                            \
    }

    for (int tp = 0; tp < 8; ++tp) {
        LSTM_STEP(hsAhi, hsAlo, hsBhi, hsBlo, 2 * tp);      // even t: read A write B
        LSTM_STEP(hsBhi, hsBlo, hsAhi, hsAlo, 2 * tp + 1);  // odd  t: read B write A
    }
#undef LSTM_STEP
#undef XV
    // t=15 (odd) wrote A planes -> h_neigh lives in hsA.

    // ---- fused combine: h' = relu(hin@Ws.T + hn@Wn.T + bs + bn) ----
    const int ng = wave & 3, ch = wave >> 2;
    const int nodeA = n0 + ng * 16 + l15;
    const int nclA  = nodeA < NNODES ? nodeA : NNODES - 1;
    short8_t ahh[4], ahl[4], anh[4], anl[4];
#pragma unroll
    for (int kc = 0; kc < 4; ++kc) {
        splitf8(hin + (size_t)nclA * 128 + kc * 32 + quad * 8, ahh[kc], ahl[kc]);
        anh[kc] = *(const short8_t*)&hsAhi[(ng * 16 + l15) * 136 + kc * 32 + quad * 8];
        anl[kc] = *(const short8_t*)&hsAlo[(ng * 16 + l15) * 136 + kc * 32 + quad * 8];
    }
    __syncthreads();   // all hin reads done before any in-place store

#pragma unroll
    for (int ct = 0; ct < 4; ++ct) {
        const int ctg = ch * 4 + ct;
        float4_t acc = (float4_t){0.f, 0.f, 0.f, 0.f};
#pragma unroll
        for (int kc = 0; kc < 4; ++kc) {
            const int kk = kc * 32 + quad * 8;
            short8_t bh, bl;
            splitf8(Ws + (size_t)(ctg * 16 + l15) * 128 + kk, bh, bl);
            acc = __builtin_amdgcn_mfma_f32_16x16x32_bf16(ahh[kc], bh, acc, 0, 0, 0);
            acc = __builtin_amdgcn_mfma_f32_16x16x32_bf16(ahh[kc], bl, acc, 0, 0, 0);
            acc = __builtin_amdgcn_mfma_f32_16x16x32_bf16(ahl[kc], bh, acc, 0, 0, 0);
            splitf8(Wn + (size_t)(ctg * 16 + l15) * 128 + kk, bh, bl);
            acc = __builtin_amdgcn_mfma_f32_16x16x32_bf16(anh[kc], bh, acc, 0, 0, 0);
            acc = __builtin_amdgcn_mfma_f32_16x16x32_bf16(anh[kc], bl, acc, 0, 0, 0);
            acc = __builtin_amdgcn_mfma_f32_16x16x32_bf16(anl[kc], bh, acc, 0, 0, 0);
        }
        const int c = ctg * 16 + l15;
        const float bb = bs[c] + bn[c];
#pragma unroll
        for (int r = 0; r < 4; ++r) {
            int rowo = n0 + ng * 16 + quad * 4 + r;
            if (rowo < NNODES) {
                float v = acc[r] + bb;
                hout[(size_t)rowo * 128 + c] = v > 0.f ? v : 0.f;
            }
        }
    }
}

// ---------------------------------------------------------------------------
// Fused MLP heads (unchanged from R12).
// ---------------------------------------------------------------------------
__global__ __launch_bounds__(256) void heads_fused(
    const float* __restrict__ hsrc,
    const float* __restrict__ clsW, const float* __restrict__ clsb,
    const float* __restrict__ clsoW, const float* __restrict__ clsob,
    const float* __restrict__ cnfW, const float* __restrict__ cnfb,
    const float* __restrict__ cnfoW, const float* __restrict__ cnfob,
    float* __restrict__ oC, float* __restrict__ oL)
{
    __shared__ short xb[64 * 132];    // activations (bf16)
    __shared__ short wb[128 * 132];   // current layer weights (bf16)

    const int tid  = threadIdx.x;
    const int wave = tid >> 6, lane = tid & 63;
    const int l15  = lane & 15, quad = lane >> 4;
    const int n0   = blockIdx.x * 64;

    {
        int row = tid >> 2, cb = (tid & 3) * 32;
        int rsrc = n0 + row; if (rsrc >= NNODES) rsrc = NNODES - 1;
        const float* src = hsrc + (size_t)rsrc * 128 + cb;
#pragma unroll
        for (int i = 0; i < 4; ++i)
            *(short8_t*)&xb[row * 132 + cb + i * 8] = cvtb8(src + i * 8);
    }

    for (int head = 0; head < 2; ++head) {
        const float* W  = head ? cnfW : clsW;
        const float* bv = head ? cnfb : clsb;

        if (head == 1) {
            __syncthreads();
            int row = tid >> 2, cb = (tid & 3) * 32;
            int rsrc = n0 + row; if (rsrc >= NNODES) rsrc = NNODES - 1;
            const float* src = hsrc + (size_t)rsrc * 128 + cb;
#pragma unroll
            for (int i = 0; i < 4; ++i)
                *(short8_t*)&xb[row * 132 + cb + i * 8] = cvtb8(src + i * 8);
        }

        for (int l = 0; l < 5; ++l) {
            __syncthreads();
            short8_t af[4];
#pragma unroll
            for (int kc = 0; kc < 4; ++kc)
                af[kc] = *(const short8_t*)&xb[(wave * 16 + l15) * 132 + kc * 32 + quad * 8];
            const float* Wl = W + (size_t)l * 16384;
#pragma unroll
            for (int i = 0; i < 8; ++i) {
                int e = i * 2048 + tid * 8;
                int r = e >> 7, c = e & 127;
                *(short8_t*)&wb[r * 132 + c] = cvtb8(Wl + e);
            }
            __syncthreads();
#pragma unroll
            for (int ct = 0; ct < 8; ++ct) {
                float4_t acc = (float4_t){0.f, 0.f, 0.f, 0.f};
#pragma unroll
                for (int kc = 0; kc < 4; ++kc) {
                    short8_t bf = *(const short8_t*)&wb[(ct * 16 + l15) * 132 + kc * 32 + quad * 8];
                    acc = __builtin_amdgcn_mfma_f32_16x16x32_bf16(af[kc], bf, acc, 0, 0, 0);
                }
                int c = ct * 16 + l15;
                float bb = bv[l * 128 + c];
#pragma unroll
                for (int r = 0; r < 4; ++r) {
                    float v = acc[r] + bb;
                    v = v > 0.f ? v : 0.f;
                    xb[(wave * 16 + quad * 4 + r) * 132 + c] = (short)f2b(v);
                }
            }
        }

        __syncthreads();
        short8_t af[4];
#pragma unroll
        for (int kc = 0; kc < 4; ++kc)
            af[kc] = *(const short8_t*)&xb[(wave * 16 + l15) * 132 + kc * 32 + quad * 8];
        if (head == 0) {
            int wr = l15 < 10 ? l15 : 9;
            float4_t acc = (float4_t){0.f, 0.f, 0.f, 0.f};
#pragma unroll
            for (int kc = 0; kc < 4; ++kc) {
                short8_t bh, bl;
                splitf8(clsoW + (size_t)wr * 128 + kc * 32 + quad * 8, bh, bl);
                acc = __builtin_amdgcn_mfma_f32_16x16x32_bf16(af[kc], bh, acc, 0, 0, 0);
                acc = __builtin_amdgcn_mfma_f32_16x16x32_bf16(af[kc], bl, acc, 0, 0, 0);
            }
            if (l15 < 10) {
                float bb = clsob[l15];
#pragma unroll
                for (int r = 0; r < 4; ++r) {
                    int row = n0 + wave * 16 + quad * 4 + r;
                    if (row < NNODES) oC[(size_t)row * 10 + l15] = acc[r] + bb;
                }
            }
        } else {
            float4_t acc = (float4_t){0.f, 0.f, 0.f, 0.f};
#pragma unroll
            for (int kc = 0; kc < 4; ++kc) {
                short8_t bh, bl;
                splitf8(cnfoW + kc * 32 + quad * 8, bh, bl);
                acc = __builtin_amdgcn_mfma_f32_16x16x32_bf16(af[kc], bh, acc, 0, 0, 0);
                acc = __builtin_amdgcn_mfma_f32_16x16x32_bf16(af[kc], bl, acc, 0, 0, 0);
            }
            if (l15 == 0) {
                float bb = cnfob[0];
#pragma unroll
                for (int r = 0; r < 4; ++r) {
                    int row = n0 + wave * 16 + quad * 4 + r;
                    if (row < NNODES) oL[row] = acc[r] + bb;
                }
            }
        }
    }
}

// ===========================================================================
extern "C" void kernel_launch(void* const* d_in, const int* in_sizes, int n_in,
                              void* d_out, int out_size, void* d_ws, size_t ws_size,
                              hipStream_t stream)
{
    const float* h0     = (const float*)d_in[0];
    const int*   nbr    = (const int*)d_in[1];
    const float* Wih    = (const float*)d_in[2];   // [2,512,128]
    const float* Whh    = (const float*)d_in[3];   // [2,512,128]
    const float* lb     = (const float*)d_in[4];   // [2,512]
    const float* Wself  = (const float*)d_in[5];   // [2,128,128]
    const float* bself  = (const float*)d_in[6];
    const float* Wneigh = (const float*)d_in[7];
    const float* bneigh = (const float*)d_in[8];
    const float* clsW   = (const float*)d_in[9];   // [5,128,128]
    const float* clsb   = (const float*)d_in[10];
    const float* clsoW  = (const float*)d_in[11];  // [10,128]
    const float* clsob  = (const float*)d_in[12];
    const float* cnfW   = (const float*)d_in[13];
    const float* cnfb   = (const float*)d_in[14];
    const float* cnfoW  = (const float*)d_in[15];  // [1,128]
    const float* cnfob  = (const float*)d_in[16];

    char* ws = (char*)d_ws;
    _Float16* Xhi = (_Float16*)ws;                 // [0, 102.4M)

    float* out = (float*)d_out;
    float* oC  = out;                   // [N,10]
    float* hO  = out + 1000000;         // [N,128]; h1/h2 live here
    float* oL  = out + 13800000;        // [N,1]

    dim3 gx(8, 1563);    // xgemm: cols fast, M=100000, NC=512
    dim3 gl(1563);       // lstm, 512 thr
    dim3 gf(1563);       // heads_fused, 256 thr

    // ---- layer 1: h1 -> d_out h slot ----
    xgemm_h<<<gx, dim3(256), 0, stream>>>(h0, Wih, lb, Xhi);
    lstm_comb<<<gl, dim3(512), 0, stream>>>(Xhi, nbr, Whh, h0,
                                            Wself, Wneigh, bself, bneigh, hO);
    // ---- layer 2: h2 -> same slot, in-place ----
    xgemm_h<<<gx, dim3(256), 0, stream>>>(hO, Wih + 65536, lb + 512, Xhi);
    lstm_comb<<<gl, dim3(512), 0, stream>>>(Xhi, nbr, Whh + 65536, hO,
                                            Wself + 16384, Wneigh + 16384,
                                            bself + 128, bneigh + 128, hO);

    // ---- heads: one fused dispatch ----
    heads_fused<<<gf, dim3(256), 0, stream>>>(hO, clsW, clsb, clsoW, clsob,
                                              cnfW, cnfb, cnfoW, cnfob, oC, oL);
}

// Round 11
// 3029.549 us; speedup vs baseline: 1.3511x; 1.0117x over previous
//
#include <hip/hip_runtime.h>
#include <stdint.h>

// GNNCell: 2x SAGEConv(lstm) + 2 MLP heads. N=100000, D=16, H=128, fp32 I/O.
// R14/15 passed 2911 us (lstm 2x~1137, WRITE 72MB no spill). Best so far.
// R16 REGRESSED 4093: cross-step X prefetch -> spill (WRITE 1.14GB).
// R17 REGRESSED 3065: fp16-X + exp2-domain bundled; spill returned
//     (WRITE 889MB) despite SMALLER nominal live set. Attribution unclear:
//     (a) exp2-domain rewrite, or (b) fp16-X register freeing letting the
//     scheduler over-hoist. absmax 0.0078 passed -> fp16-X precision OK.
// R18: CLEAN SPLIT = R14 + fp16-only X, nothing else. ln-domain
//     activations, unscaled splitf8 Whh init, perm-pack — all byte-identical
//     to R14. Only X format changed: fp16 store (no i8-lo), 2 loads/nt,
//     lo-unpack gone (~240 VALU ops/step/lane), xl4 regs freed.
//     WRITE ~72MB -> exp2 was the culprit (keep this). WRITE ~880MB ->
//     fp16-X destabilizes regalloc (revert to R14 next).

typedef __attribute__((ext_vector_type(8))) short short8_t;
typedef __attribute__((ext_vector_type(4))) float float4_t;
typedef __attribute__((ext_vector_type(4))) unsigned uint4_t;
typedef _Float16 half8_t __attribute__((ext_vector_type(8)));

#define NNODES 100000
#define DNB 16

__device__ __forceinline__ float fsigf(float x) {
    return __builtin_amdgcn_rcpf(1.f + __expf(-x));
}
__device__ __forceinline__ float ftanhf(float x) {
    return 1.f - 2.f * __builtin_amdgcn_rcpf(1.f + __expf(2.f * x));
}
__device__ __forceinline__ unsigned f2b(float f) {  // RNE f32->bf16 (finite)
    unsigned u = __float_as_uint(f);
    return (u + 0x7FFFu + ((u >> 16) & 1u)) >> 16;
}
__device__ __forceinline__ float blo(unsigned u) { return __uint_as_float(u << 16); }
__device__ __forceinline__ float bhi(unsigned u) { return __uint_as_float(u & 0xFFFF0000u); }
// pack hi16(u0) | hi16(u1)<<16 in ONE v_perm_b32 (builtin -> no reg pinning)
__device__ __forceinline__ unsigned pkhi(unsigned u0, unsigned u1) {
    return __builtin_amdgcn_perm(u1, u0, 0x07060302u);
}
// f2b-based split: compiler-friendly (values can migrate to AGPRs).
__device__ __forceinline__ void splitf8(const float* __restrict__ p, short8_t& hi, short8_t& lo) {
    float4_t a = *(const float4_t*)p;
    float4_t b = *(const float4_t*)(p + 4);
#pragma unroll
    for (int j = 0; j < 8; ++j) {
        float x = j < 4 ? a[j] : b[j - 4];
        unsigned hb = f2b(x);
        float hf = __uint_as_float(hb << 16);
        unsigned lb = f2b(x - hf);
        hi[j] = (short)hb;
        lo[j] = (short)lb;
    }
}
// packed f32 pair -> 2x bf16 (inline asm: ONLY transient values in
// low-pressure kernels; never in lstm_comb).
__device__ __forceinline__ unsigned cvtpk(float lo, float hi) {
    unsigned r;
    asm("v_cvt_pk_bf16_f32 %0, %1, %2" : "=v"(r) : "v"(lo), "v"(hi));
    return r;
}
__device__ __forceinline__ void splitf8_pk(const float* __restrict__ p, short8_t& hi, short8_t& lo) {
    float4_t a = *(const float4_t*)p;
    float4_t b = *(const float4_t*)(p + 4);
    unsigned h0 = cvtpk(a[0], a[1]), h1 = cvtpk(a[2], a[3]);
    unsigned h2 = cvtpk(b[0], b[1]), h3 = cvtpk(b[2], b[3]);
    unsigned l0 = cvtpk(a[0] - blo(h0), a[1] - bhi(h0));
    unsigned l1 = cvtpk(a[2] - blo(h1), a[3] - bhi(h1));
    unsigned l2 = cvtpk(b[0] - blo(h2), b[1] - bhi(h2));
    unsigned l3 = cvtpk(b[2] - blo(h3), b[3] - bhi(h3));
    union { uint4_t u; short8_t s; } ch, cl;
    ch.u = (uint4_t){h0, h1, h2, h3};
    cl.u = (uint4_t){l0, l1, l2, l3};
    hi = ch.s;
    lo = cl.s;
}
// fp32[8] -> bf16x8 (plain cast, head path)
__device__ __forceinline__ short8_t cvtb8(const float* __restrict__ p) {
    float4_t a = *(const float4_t*)p;
    float4_t b = *(const float4_t*)(p + 4);
    union { uint4_t u; short8_t s; } c;
    c.u = (uint4_t){cvtpk(a[0], a[1]), cvtpk(a[2], a[3]),
                    cvtpk(b[0], b[1]), cvtpk(b[2], b[3])};
    return c.s;
}

// ---------------------------------------------------------------------------
// X = h @ Wih.T + b, split-bf16 3-MFMA, stored fp16 ONLY.
// GATE-INTERLEAVED output: element c = g*128+j at node*512 + j*4 + g.
// ---------------------------------------------------------------------------
__global__ __launch_bounds__(256) void xgemm_h(
    const float* __restrict__ A, const float* __restrict__ B,
    const float* __restrict__ bias, _Float16* __restrict__ Chi)
{
    const int tid  = threadIdx.x;
    const int wave = tid >> 6, lane = tid & 63;
    const int l15  = lane & 15, quad = lane >> 4;
    const int r0   = blockIdx.y * 64 + wave * 16;
    const int c0   = blockIdx.x * 64;

    int arow = r0 + l15;
    if (arow >= NNODES) arow = NNODES - 1;

    float4_t acc[4];
#pragma unroll
    for (int ct = 0; ct < 4; ++ct) acc[ct] = (float4_t){0.f, 0.f, 0.f, 0.f};

#pragma unroll
    for (int kc = 0; kc < 4; ++kc) {
        const int kk = kc * 32 + quad * 8;
        short8_t ah, al;
        splitf8_pk(A + (size_t)arow * 128 + kk, ah, al);
#pragma unroll
        for (int ct = 0; ct < 4; ++ct) {
            short8_t bh, bl;
            splitf8_pk(B + (size_t)(c0 + ct * 16 + l15) * 128 + kk, bh, bl);
            acc[ct] = __builtin_amdgcn_mfma_f32_16x16x32_bf16(ah, bh, acc[ct], 0, 0, 0);
            acc[ct] = __builtin_amdgcn_mfma_f32_16x16x32_bf16(ah, bl, acc[ct], 0, 0, 0);
            acc[ct] = __builtin_amdgcn_mfma_f32_16x16x32_bf16(al, bh, acc[ct], 0, 0, 0);
        }
    }

#pragma unroll
    for (int ct = 0; ct < 4; ++ct) {
        int c = c0 + ct * 16 + l15;
        float bb = bias[c];
        const int jj = c & 127, gg = c >> 7;          // gate-interleaved slot
#pragma unroll
        for (int r = 0; r < 4; ++r) {
            int rowo = r0 + quad * 4 + r;
            if (rowo < NNODES)
                Chi[(size_t)rowo * 512 + jj * 4 + gg] = (_Float16)(acc[ct][r] + bb);
        }
    }
}

// ---------------------------------------------------------------------------
// Fused 16-step LSTM + combine — R14 structure (proven no-spill), fp16 X.
// Block = 64 nodes, 512 threads (8 waves); wave owns j-slice [16w,16w+16)
// for all 4 gates. hs double-buffered bf16 hi/lo LDS planes, 1 barrier/step.
// X: fp16 only, 2x16B loads/lane/nt at step start, consumed post-GEMM.
// nbr staged in LDS. hs re-pack: truncation split + v_perm (12 ops/nt).
// Activations: ln-domain fsigf/ftanhf (byte-identical to R14).
// ---------------------------------------------------------------------------
__global__ __launch_bounds__(512, 2) void lstm_comb(
    const _Float16* __restrict__ Xhi,
    const int* __restrict__ nbr, const float* __restrict__ Whh,
    const float* hin, const float* __restrict__ Ws,
    const float* __restrict__ Wn, const float* __restrict__ bs,
    const float* __restrict__ bn, float* hout)
{
    __shared__ short hsAhi[64 * 136], hsAlo[64 * 136];
    __shared__ short hsBhi[64 * 136], hsBlo[64 * 136];
    __shared__ int   nbrs[64 * 17];

    const int tid  = threadIdx.x;
    const int wave = tid >> 6, lane = tid & 63;
    const int l15  = lane & 15, quad = lane >> 4;
    const int n0   = blockIdx.x * 64;
    const int jb   = wave * 16;
    const int xoff = jb * 4 + quad * 16;   // gate-interleaved lane offset

    for (int i = tid; i < 64 * 136 / 2; i += 512) {
        ((unsigned*)hsAhi)[i] = 0;
        ((unsigned*)hsAlo)[i] = 0;
    }
    for (int i = tid; i < 64 * DNB; i += 512) {
        int node = n0 + (i >> 4);
        if (node >= NNODES) node = NNODES - 1;
        nbrs[(i >> 4) * 17 + (i & 15)] = nbr[node * DNB + (i & 15)];
    }

    // Whh split fragments: 4 gates x 4 k-chunks x (hi,lo) = 32 frags
    short8_t whi[4][4], wlo[4][4];
#pragma unroll
    for (int g = 0; g < 4; ++g)
#pragma unroll
        for (int kc = 0; kc < 4; ++kc)
            splitf8(Whh + (size_t)(g * 128 + jb + l15) * 128 + kc * 32 + quad * 8,
                    whi[g][kc], wlo[g][kc]);

    float cs[4][4], nh[4][4];
#pragma unroll
    for (int a = 0; a < 4; ++a)
#pragma unroll
        for (int b = 0; b < 4; ++b) { cs[a][b] = 0.f; nh[a][b] = 0.f; }

    __syncthreads();

// hi value (g,r) lives at vector slot r*4+g across xh0/xh1.
#define XV(nt, r, g)                                                                \
    ((float)(((r) * 4 + (g)) < 8 ? xh0[nt][(r) * 4 + (g)] : xh1[nt][(r) * 4 + (g) - 8]))

#define LSTM_STEP(rdHi, rdLo, wrHi, wrLo, T)                                        \
    {                                                                               \
        half8_t xh0[4], xh1[4];                                                     \
        _Pragma("unroll")                                                           \
        for (int nt = 0; nt < 4; ++nt) {                                            \
            int gi = nbrs[(nt * 16 + l15) * 17 + (T)];                              \
            size_t xb = (size_t)gi * 512 + xoff;                                    \
            xh0[nt] = *(const half8_t*)(Xhi + xb);                                  \
            xh1[nt] = *(const half8_t*)(Xhi + xb + 8);                              \
        }                                                                           \
        _Pragma("unroll")                                                           \
        for (int nt = 0; nt < 4; ++nt) {                                            \
            short8_t hfh[4], hfl[4];                                                \
            _Pragma("unroll")                                                       \
            for (int kc = 0; kc < 4; ++kc) {                                        \
                hfh[kc] = *(const short8_t*)&(rdHi)[(nt * 16 + l15) * 136 + kc * 32 + quad * 8]; \
                hfl[kc] = *(const short8_t*)&(rdLo)[(nt * 16 + l15) * 136 + kc * 32 + quad * 8]; \
            }                                                                       \
            float4_t ac[4];                                                         \
            _Pragma("unroll")                                                       \
            for (int g = 0; g < 4; ++g) {                                           \
                float4_t a = (float4_t){0.f, 0.f, 0.f, 0.f};                        \
                _Pragma("unroll")                                                   \
                for (int kc = 0; kc < 4; ++kc) {                                    \
                    a = __builtin_amdgcn_mfma_f32_16x16x32_bf16(whi[g][kc], hfh[kc], a, 0, 0, 0); \
                    a = __builtin_amdgcn_mfma_f32_16x16x32_bf16(whi[g][kc], hfl[kc], a, 0, 0, 0); \
                    a = __builtin_amdgcn_mfma_f32_16x16x32_bf16(wlo[g][kc], hfh[kc], a, 0, 0, 0); \
                }                                                                   \
                ac[g] = a;                                                          \
            }                                                                       \
            _Pragma("unroll")                                                       \
            for (int r = 0; r < 4; ++r) {                                           \
                float iv = ac[0][r] + XV(nt, r, 0);                                 \
                float fv = ac[1][r] + XV(nt, r, 1);                                 \
                float gv = ac[2][r] + XV(nt, r, 2);                                 \
                float ov = ac[3][r] + XV(nt, r, 3);                                 \
                float c = fsigf(fv) * cs[nt][r] + fsigf(iv) * ftanhf(gv);           \
                cs[nt][r] = c;                                                      \
                nh[nt][r] = fsigf(ov) * ftanhf(c);                                  \
            }                                                                       \
        }                                                                           \
        _Pragma("unroll")                                                           \
        for (int nt = 0; nt < 4; ++nt) {                                            \
            unsigned u0 = __float_as_uint(nh[nt][0]);                               \
            unsigned u1 = __float_as_uint(nh[nt][1]);                               \
            unsigned u2 = __float_as_uint(nh[nt][2]);                               \
            unsigned u3 = __float_as_uint(nh[nt][3]);                               \
            unsigned r0 = __float_as_uint(nh[nt][0] - bhi(u0));                     \
            unsigned r1 = __float_as_uint(nh[nt][1] - bhi(u1));                     \
            unsigned r2 = __float_as_uint(nh[nt][2] - bhi(u2));                     \
            unsigned r3 = __float_as_uint(nh[nt][3] - bhi(u3));                     \
            uint2 ph, pl;                                                           \
            ph.x = pkhi(u0, u1); ph.y = pkhi(u2, u3);                               \
            pl.x = pkhi(r0, r1); pl.y = pkhi(r2, r3);                               \
            const int o = (nt * 16 + l15) * 136 + jb + quad * 4;                    \
            *(uint2*)&(wrHi)[o] = ph;                                               \
            *(uint2*)&(wrLo)[o] = pl;                                               \
        }                                                                           \
        __syncthreads();                                                            \
    }

    for (int tp = 0; tp < 8; ++tp) {
        LSTM_STEP(hsAhi, hsAlo, hsBhi, hsBlo, 2 * tp);      // even t: read A write B
        LSTM_STEP(hsBhi, hsBlo, hsAhi, hsAlo, 2 * tp + 1);  // odd  t: read B write A
    }
#undef LSTM_STEP
#undef XV
    // t=15 (odd) wrote A planes -> h_neigh lives in hsA.

    // ---- fused combine: h' = relu(hin@Ws.T + hn@Wn.T + bs + bn) ----
    const int ng = wave & 3, ch = wave >> 2;
    const int nodeA = n0 + ng * 16 + l15;
    const int nclA  = nodeA < NNODES ? nodeA : NNODES - 1;
    short8_t ahh[4], ahl[4], anh[4], anl[4];
#pragma unroll
    for (int kc = 0; kc < 4; ++kc) {
        splitf8(hin + (size_t)nclA * 128 + kc * 32 + quad * 8, ahh[kc], ahl[kc]);
        anh[kc] = *(const short8_t*)&hsAhi[(ng * 16 + l15) * 136 + kc * 32 + quad * 8];
        anl[kc] = *(const short8_t*)&hsAlo[(ng * 16 + l15) * 136 + kc * 32 + quad * 8];
    }
    __syncthreads();   // all hin reads done before any in-place store

#pragma unroll
    for (int ct = 0; ct < 4; ++ct) {
        const int ctg = ch * 4 + ct;
        float4_t acc = (float4_t){0.f, 0.f, 0.f, 0.f};
#pragma unroll
        for (int kc = 0; kc < 4; ++kc) {
            const int kk = kc * 32 + quad * 8;
            short8_t bh, bl;
            splitf8(Ws + (size_t)(ctg * 16 + l15) * 128 + kk, bh, bl);
            acc = __builtin_amdgcn_mfma_f32_16x16x32_bf16(ahh[kc], bh, acc, 0, 0, 0);
            acc = __builtin_amdgcn_mfma_f32_16x16x32_bf16(ahh[kc], bl, acc, 0, 0, 0);
            acc = __builtin_amdgcn_mfma_f32_16x16x32_bf16(ahl[kc], bh, acc, 0, 0, 0);
            splitf8(Wn + (size_t)(ctg * 16 + l15) * 128 + kk, bh, bl);
            acc = __builtin_amdgcn_mfma_f32_16x16x32_bf16(anh[kc], bh, acc, 0, 0, 0);
            acc = __builtin_amdgcn_mfma_f32_16x16x32_bf16(anh[kc], bl, acc, 0, 0, 0);
            acc = __builtin_amdgcn_mfma_f32_16x16x32_bf16(anl[kc], bh, acc, 0, 0, 0);
        }
        const int c = ctg * 16 + l15;
        const float bb = bs[c] + bn[c];
#pragma unroll
        for (int r = 0; r < 4; ++r) {
            int rowo = n0 + ng * 16 + quad * 4 + r;
            if (rowo < NNODES) {
                float v = acc[r] + bb;
                hout[(size_t)rowo * 128 + c] = v > 0.f ? v : 0.f;
            }
        }
    }
}

// ---------------------------------------------------------------------------
// Fused MLP heads (unchanged from R12).
// ---------------------------------------------------------------------------
__global__ __launch_bounds__(256) void heads_fused(
    const float* __restrict__ hsrc,
    const float* __restrict__ clsW, const float* __restrict__ clsb,
    const float* __restrict__ clsoW, const float* __restrict__ clsob,
    const float* __restrict__ cnfW, const float* __restrict__ cnfb,
    const float* __restrict__ cnfoW, const float* __restrict__ cnfob,
    float* __restrict__ oC, float* __restrict__ oL)
{
    __shared__ short xb[64 * 132];    // activations (bf16)
    __shared__ short wb[128 * 132];   // current layer weights (bf16)

    const int tid  = threadIdx.x;
    const int wave = tid >> 6, lane = tid & 63;
    const int l15  = lane & 15, quad = lane >> 4;
    const int n0   = blockIdx.x * 64;

    {
        int row = tid >> 2, cb = (tid & 3) * 32;
        int rsrc = n0 + row; if (rsrc >= NNODES) rsrc = NNODES - 1;
        const float* src = hsrc + (size_t)rsrc * 128 + cb;
#pragma unroll
        for (int i = 0; i < 4; ++i)
            *(short8_t*)&xb[row * 132 + cb + i * 8] = cvtb8(src + i * 8);
    }

    for (int head = 0; head < 2; ++head) {
        const float* W  = head ? cnfW : clsW;
        const float* bv = head ? cnfb : clsb;

        if (head == 1) {
            __syncthreads();
            int row = tid >> 2, cb = (tid & 3) * 32;
            int rsrc = n0 + row; if (rsrc >= NNODES) rsrc = NNODES - 1;
            const float* src = hsrc + (size_t)rsrc * 128 + cb;
#pragma unroll
            for (int i = 0; i < 4; ++i)
                *(short8_t*)&xb[row * 132 + cb + i * 8] = cvtb8(src + i * 8);
        }

        for (int l = 0; l < 5; ++l) {
            __syncthreads();
            short8_t af[4];
#pragma unroll
            for (int kc = 0; kc < 4; ++kc)
                af[kc] = *(const short8_t*)&xb[(wave * 16 + l15) * 132 + kc * 32 + quad * 8];
            const float* Wl = W + (size_t)l * 16384;
#pragma unroll
            for (int i = 0; i < 8; ++i) {
                int e = i * 2048 + tid * 8;
                int r = e >> 7, c = e & 127;
                *(short8_t*)&wb[r * 132 + c] = cvtb8(Wl + e);
            }
            __syncthreads();
#pragma unroll
            for (int ct = 0; ct < 8; ++ct) {
                float4_t acc = (float4_t){0.f, 0.f, 0.f, 0.f};
#pragma unroll
                for (int kc = 0; kc < 4; ++kc) {
                    short8_t bf = *(const short8_t*)&wb[(ct * 16 + l15) * 132 + kc * 32 + quad * 8];
                    acc = __builtin_amdgcn_mfma_f32_16x16x32_bf16(af[kc], bf, acc, 0, 0, 0);
                }
                int c = ct * 16 + l15;
                float bb = bv[l * 128 + c];
#pragma unroll
                for (int r = 0; r < 4; ++r) {
                    float v = acc[r] + bb;
                    v = v > 0.f ? v : 0.f;
                    xb[(wave * 16 + quad * 4 + r) * 132 + c] = (short)f2b(v);
                }
            }
        }

        __syncthreads();
        short8_t af[4];
#pragma unroll
        for (int kc = 0; kc < 4; ++kc)
            af[kc] = *(const short8_t*)&xb[(wave * 16 + l15) * 132 + kc * 32 + quad * 8];
        if (head == 0) {
            int wr = l15 < 10 ? l15 : 9;
            float4_t acc = (float4_t){0.f, 0.f, 0.f, 0.f};
#pragma unroll
            for (int kc = 0; kc < 4; ++kc) {
                short8_t bh, bl;
                splitf8(clsoW + (size_t)wr * 128 + kc * 32 + quad * 8, bh, bl);
                acc = __builtin_amdgcn_mfma_f32_16x16x32_bf16(af[kc], bh, acc, 0, 0, 0);
                acc = __builtin_amdgcn_mfma_f32_16x16x32_bf16(af[kc], bl, acc, 0, 0, 0);
            }
            if (l15 < 10) {
                float bb = clsob[l15];
#pragma unroll
                for (int r = 0; r < 4; ++r) {
                    int row = n0 + wave * 16 + quad * 4 + r;
                    if (row < NNODES) oC[(size_t)row * 10 + l15] = acc[r] + bb;
                }
            }
        } else {
            float4_t acc = (float4_t){0.f, 0.f, 0.f, 0.f};
#pragma unroll
            for (int kc = 0; kc < 4; ++kc) {
                short8_t bh, bl;
                splitf8(cnfoW + kc * 32 + quad * 8, bh, bl);
                acc = __builtin_amdgcn_mfma_f32_16x16x32_bf16(af[kc], bh, acc, 0, 0, 0);
                acc = __builtin_amdgcn_mfma_f32_16x16x32_bf16(af[kc], bl, acc, 0, 0, 0);
            }
            if (l15 == 0) {
                float bb = cnfob[0];
#pragma unroll
                for (int r = 0; r < 4; ++r) {
                    int row = n0 + wave * 16 + quad * 4 + r;
                    if (row < NNODES) oL[row] = acc[r] + bb;
                }
            }
        }
    }
}

// ===========================================================================
extern "C" void kernel_launch(void* const* d_in, const int* in_sizes, int n_in,
                              void* d_out, int out_size, void* d_ws, size_t ws_size,
                              hipStream_t stream)
{
    const float* h0     = (const float*)d_in[0];
    const int*   nbr    = (const int*)d_in[1];
    const float* Wih    = (const float*)d_in[2];   // [2,512,128]
    const float* Whh    = (const float*)d_in[3];   // [2,512,128]
    const float* lb     = (const float*)d_in[4];   // [2,512]
    const float* Wself  = (const float*)d_in[5];   // [2,128,128]
    const float* bself  = (const float*)d_in[6];
    const float* Wneigh = (const float*)d_in[7];
    const float* bneigh = (const float*)d_in[8];
    const float* clsW   = (const float*)d_in[9];   // [5,128,128]
    const float* clsb   = (const float*)d_in[10];
    const float* clsoW  = (const float*)d_in[11];  // [10,128]
    const float* clsob  = (const float*)d_in[12];
    const float* cnfW   = (const float*)d_in[13];
    const float* cnfb   = (const float*)d_in[14];
    const float* cnfoW  = (const float*)d_in[15];  // [1,128]
    const float* cnfob  = (const float*)d_in[16];

    char* ws = (char*)d_ws;
    _Float16* Xhi = (_Float16*)ws;                 // [0, 102.4M)

    float* out = (float*)d_out;
    float* oC  = out;                   // [N,10]
    float* hO  = out + 1000000;         // [N,128]; h1/h2 live here
    float* oL  = out + 13800000;        // [N,1]

    dim3 gx(8, 1563);    // xgemm: cols fast, M=100000, NC=512
    dim3 gl(1563);       // lstm, 512 thr
    dim3 gf(1563);       // heads_fused, 256 thr

    // ---- layer 1: h1 -> d_out h slot ----
    xgemm_h<<<gx, dim3(256), 0, stream>>>(h0, Wih, lb, Xhi);
    lstm_comb<<<gl, dim3(512), 0, stream>>>(Xhi, nbr, Whh, h0,
                                            Wself, Wneigh, bself, bneigh, hO);
    // ---- layer 2: h2 -> same slot, in-place ----
    xgemm_h<<<gx, dim3(256), 0, stream>>>(hO, Wih + 65536, lb + 512, Xhi);
    lstm_comb<<<gl, dim3(512), 0, stream>>>(Xhi, nbr, Whh + 65536, hO,
                                            Wself + 16384, Wneigh + 16384,
                                            bself + 128, bneigh + 128, hO);

    // ---- heads: one fused dispatch ----
    heads_fused<<<gf, dim3(256), 0, stream>>>(hO, clsW, clsb, clsoW, clsob,
                                              cnfW, cnfb, cnfoW, cnfob, oC, oL);
}

// Round 12
// 2746.005 us; speedup vs baseline: 1.4906x; 1.1033x over previous
//
#include <hip/hip_runtime.h>
#include <stdint.h>

// GNNCell: 2x SAGEConv(lstm) + 2 MLP heads. N=100000, D=16, H=128, fp32 I/O.
// R14/15 passed 2911 us (lstm 2x~1137, WRITE 72MB no spill). BEST.
// R16/R17/R18 all REGRESSED via lstm register-allocation destabilization
//     (cross-step prefetch / fp32-X / fp16-X each -> scratch spill, WRITE
//     0.85-1.14GB). Five data points: R14's lstm_comb is a razor-edge
//     register equilibrium; ANY change to its live set spills. lstm CLOSED.
// R19: R14 lstm byte-identical + gate-major xgemm tiling: block covers the
//     SAME 16-j group across all 4 gates (c = g*128+j0+l15), so the
//     gate-interleaved output packs into one 8B fp16 + one 4B i8 store per
//     (lane,row), fully contiguous across 16 lanes (was 2B stores at
//     stride 8 = ~25% coalescing on 154MB). 4x write efficiency, zero
//     lstm risk, bit-identical math.
// Precision: X fp16-hi + i8-lo(2^-15); recurrence split-bf16 3-MFMA with
// truncated-hi hs (lo-compensated); heads bf16.

typedef __attribute__((ext_vector_type(8))) short short8_t;
typedef __attribute__((ext_vector_type(4))) float float4_t;
typedef __attribute__((ext_vector_type(4))) unsigned uint4_t;
typedef _Float16 half8_t __attribute__((ext_vector_type(8)));

#define NNODES 100000
#define DNB 16
#define LOSCALE 32768.0f
#define LOINV   3.0517578125e-5f   // 2^-15

__device__ __forceinline__ float fsigf(float x) {
    return __builtin_amdgcn_rcpf(1.f + __expf(-x));
}
__device__ __forceinline__ float ftanhf(float x) {
    return 1.f - 2.f * __builtin_amdgcn_rcpf(1.f + __expf(2.f * x));
}
__device__ __forceinline__ unsigned f2b(float f) {  // RNE f32->bf16 (finite)
    unsigned u = __float_as_uint(f);
    return (u + 0x7FFFu + ((u >> 16) & 1u)) >> 16;
}
__device__ __forceinline__ float blo(unsigned u) { return __uint_as_float(u << 16); }
__device__ __forceinline__ float bhi(unsigned u) { return __uint_as_float(u & 0xFFFF0000u); }
// pack hi16(u0) | hi16(u1)<<16 in ONE v_perm_b32 (builtin -> no reg pinning)
__device__ __forceinline__ unsigned pkhi(unsigned u0, unsigned u1) {
    return __builtin_amdgcn_perm(u1, u0, 0x07060302u);
}
// f2b-based split: compiler-friendly (values can migrate to AGPRs).
__device__ __forceinline__ void splitf8(const float* __restrict__ p, short8_t& hi, short8_t& lo) {
    float4_t a = *(const float4_t*)p;
    float4_t b = *(const float4_t*)(p + 4);
#pragma unroll
    for (int j = 0; j < 8; ++j) {
        float x = j < 4 ? a[j] : b[j - 4];
        unsigned hb = f2b(x);
        float hf = __uint_as_float(hb << 16);
        unsigned lb = f2b(x - hf);
        hi[j] = (short)hb;
        lo[j] = (short)lb;
    }
}
// packed f32 pair -> 2x bf16 (inline asm: ONLY transient values in
// low-pressure kernels; never in lstm_comb).
__device__ __forceinline__ unsigned cvtpk(float lo, float hi) {
    unsigned r;
    asm("v_cvt_pk_bf16_f32 %0, %1, %2" : "=v"(r) : "v"(lo), "v"(hi));
    return r;
}
__device__ __forceinline__ void splitf8_pk(const float* __restrict__ p, short8_t& hi, short8_t& lo) {
    float4_t a = *(const float4_t*)p;
    float4_t b = *(const float4_t*)(p + 4);
    unsigned h0 = cvtpk(a[0], a[1]), h1 = cvtpk(a[2], a[3]);
    unsigned h2 = cvtpk(b[0], b[1]), h3 = cvtpk(b[2], b[3]);
    unsigned l0 = cvtpk(a[0] - blo(h0), a[1] - bhi(h0));
    unsigned l1 = cvtpk(a[2] - blo(h1), a[3] - bhi(h1));
    unsigned l2 = cvtpk(b[0] - blo(h2), b[1] - bhi(h2));
    unsigned l3 = cvtpk(b[2] - blo(h3), b[3] - bhi(h3));
    union { uint4_t u; short8_t s; } ch, cl;
    ch.u = (uint4_t){h0, h1, h2, h3};
    cl.u = (uint4_t){l0, l1, l2, l3};
    hi = ch.s;
    lo = cl.s;
}
// fp32[8] -> bf16x8 (plain cast, head path)
__device__ __forceinline__ short8_t cvtb8(const float* __restrict__ p) {
    float4_t a = *(const float4_t*)p;
    float4_t b = *(const float4_t*)(p + 4);
    union { uint4_t u; short8_t s; } c;
    c.u = (uint4_t){cvtpk(a[0], a[1]), cvtpk(a[2], a[3]),
                    cvtpk(b[0], b[1]), cvtpk(b[2], b[3])};
    return c.s;
}

// ---------------------------------------------------------------------------
// X = h @ Wih.T + b, split-bf16 3-MFMA (rel ~2^-16), stored fp16-hi + i8-lo.
// GATE-MAJOR tiling: block covers j-group j0=bx*16 across ALL 4 gates
// (c = g*128 + j0 + l15). Epilogue packs the 4 gate values of one (row,j)
// into ONE 8B fp16 store + ONE 4B i8 store at node*512 + j*4 (+g packed),
// contiguous across the 16 l15 lanes -> full write coalescing.
// Layout (reader side) unchanged: element c=g*128+j at node*512 + j*4 + g.
// ---------------------------------------------------------------------------
__global__ __launch_bounds__(256) void xgemm_split(
    const float* __restrict__ A, const float* __restrict__ B,
    const float* __restrict__ bias, _Float16* __restrict__ Chi,
    char* __restrict__ Clo)
{
    const int tid  = threadIdx.x;
    const int wave = tid >> 6, lane = tid & 63;
    const int l15  = lane & 15, quad = lane >> 4;
    const int r0   = blockIdx.y * 64 + wave * 16;
    const int j0   = blockIdx.x * 16;

    int arow = r0 + l15;
    if (arow >= NNODES) arow = NNODES - 1;

    float4_t acc[4];   // acc[g]
#pragma unroll
    for (int g = 0; g < 4; ++g) acc[g] = (float4_t){0.f, 0.f, 0.f, 0.f};

#pragma unroll
    for (int kc = 0; kc < 4; ++kc) {
        const int kk = kc * 32 + quad * 8;
        short8_t ah, al;
        splitf8_pk(A + (size_t)arow * 128 + kk, ah, al);
#pragma unroll
        for (int g = 0; g < 4; ++g) {
            short8_t bh, bl;
            splitf8_pk(B + (size_t)(g * 128 + j0 + l15) * 128 + kk, bh, bl);
            acc[g] = __builtin_amdgcn_mfma_f32_16x16x32_bf16(ah, bh, acc[g], 0, 0, 0);
            acc[g] = __builtin_amdgcn_mfma_f32_16x16x32_bf16(ah, bl, acc[g], 0, 0, 0);
            acc[g] = __builtin_amdgcn_mfma_f32_16x16x32_bf16(al, bh, acc[g], 0, 0, 0);
        }
    }

    float bb[4];
#pragma unroll
    for (int g = 0; g < 4; ++g) bb[g] = bias[g * 128 + j0 + l15];

#pragma unroll
    for (int r = 0; r < 4; ++r) {
        int rowo = r0 + quad * 4 + r;
        if (rowo < NNODES) {
            union { uint2 u; _Float16 h[4]; } P;
            unsigned pl = 0;
#pragma unroll
            for (int g = 0; g < 4; ++g) {
                float v = acc[g][r] + bb[g];
                _Float16 hi = (_Float16)v;
                float res = v - (float)hi;
                int q = (int)rintf(res * LOSCALE);
                q = q > 127 ? 127 : (q < -127 ? -127 : q);
                P.h[g] = hi;
                pl |= ((unsigned)q & 0xFFu) << (g * 8);
            }
            *(uint2*)&Chi[(size_t)rowo * 512 + (j0 + l15) * 4] = P.u;
            *(unsigned*)&Clo[(size_t)rowo * 512 + (j0 + l15) * 4] = pl;
        }
    }
}

// ---------------------------------------------------------------------------
// Fused 16-step LSTM + combine — R14 BYTE-IDENTICAL (proven no-spill).
// Block = 64 nodes, 512 threads (8 waves); wave owns j-slice [16w,16w+16)
// for all 4 gates. hs double-buffered bf16 hi/lo LDS planes, 1 barrier/step.
// X gathers gate-interleaved 3x16B/lane/nt at step start, consumed after
// each nt's MFMA chain. nbr staged in LDS.
// hs re-pack: truncation split + v_perm packing (12 ops/nt, builtin only).
// ---------------------------------------------------------------------------
__global__ __launch_bounds__(512, 2) void lstm_comb(
    const _Float16* __restrict__ Xhi, const char* __restrict__ Xlo,
    const int* __restrict__ nbr, const float* __restrict__ Whh,
    const float* hin, const float* __restrict__ Ws,
    const float* __restrict__ Wn, const float* __restrict__ bs,
    const float* __restrict__ bn, float* hout)
{
    __shared__ short hsAhi[64 * 136], hsAlo[64 * 136];
    __shared__ short hsBhi[64 * 136], hsBlo[64 * 136];
    __shared__ int   nbrs[64 * 17];

    const int tid  = threadIdx.x;
    const int wave = tid >> 6, lane = tid & 63;
    const int l15  = lane & 15, quad = lane >> 4;
    const int n0   = blockIdx.x * 64;
    const int jb   = wave * 16;
    const int xoff = jb * 4 + quad * 16;   // gate-interleaved lane offset

    for (int i = tid; i < 64 * 136 / 2; i += 512) {
        ((unsigned*)hsAhi)[i] = 0;
        ((unsigned*)hsAlo)[i] = 0;
    }
    for (int i = tid; i < 64 * DNB; i += 512) {
        int node = n0 + (i >> 4);
        if (node >= NNODES) node = NNODES - 1;
        nbrs[(i >> 4) * 17 + (i & 15)] = nbr[node * DNB + (i & 15)];
    }

    // Whh split fragments: 4 gates x 4 k-chunks x (hi,lo) = 32 frags
    short8_t whi[4][4], wlo[4][4];
#pragma unroll
    for (int g = 0; g < 4; ++g)
#pragma unroll
        for (int kc = 0; kc < 4; ++kc)
            splitf8(Whh + (size_t)(g * 128 + jb + l15) * 128 + kc * 32 + quad * 8,
                    whi[g][kc], wlo[g][kc]);

    float cs[4][4], nh[4][4];
#pragma unroll
    for (int a = 0; a < 4; ++a)
#pragma unroll
        for (int b = 0; b < 4; ++b) { cs[a][b] = 0.f; nh[a][b] = 0.f; }

    __syncthreads();

// hi value (g,r) lives at vector slot r*4+g; lo byte g of word r.
#define XV(nt, r, g)                                                                \
    ((float)(((r) * 4 + (g)) < 8 ? xh0[nt][(r) * 4 + (g)] : xh1[nt][(r) * 4 + (g) - 8]) \
     + (float)((signed char)(xl4[nt][(r)] >> ((g) * 8))) * LOINV)

#define LSTM_STEP(rdHi, rdLo, wrHi, wrLo, T)                                        \
    {                                                                               \
        half8_t xh0[4], xh1[4]; uint4_t xl4[4];                                     \
        _Pragma("unroll")                                                           \
        for (int nt = 0; nt < 4; ++nt) {                                            \
            int gi = nbrs[(nt * 16 + l15) * 17 + (T)];                              \
            size_t xb = (size_t)gi * 512 + xoff;                                    \
            xh0[nt] = *(const half8_t*)(Xhi + xb);                                  \
            xh1[nt] = *(const half8_t*)(Xhi + xb + 8);                              \
            xl4[nt] = *(const uint4_t*)(Xlo + xb);                                  \
        }                                                                           \
        _Pragma("unroll")                                                           \
        for (int nt = 0; nt < 4; ++nt) {                                            \
            short8_t hfh[4], hfl[4];                                                \
            _Pragma("unroll")                                                       \
            for (int kc = 0; kc < 4; ++kc) {                                        \
                hfh[kc] = *(const short8_t*)&(rdHi)[(nt * 16 + l15) * 136 + kc * 32 + quad * 8]; \
                hfl[kc] = *(const short8_t*)&(rdLo)[(nt * 16 + l15) * 136 + kc * 32 + quad * 8]; \
            }                                                                       \
            float4_t ac[4];                                                         \
            _Pragma("unroll")                                                       \
            for (int g = 0; g < 4; ++g) {                                           \
                float4_t a = (float4_t){0.f, 0.f, 0.f, 0.f};                        \
                _Pragma("unroll")                                                   \
                for (int kc = 0; kc < 4; ++kc) {                                    \
                    a = __builtin_amdgcn_mfma_f32_16x16x32_bf16(whi[g][kc], hfh[kc], a, 0, 0, 0); \
                    a = __builtin_amdgcn_mfma_f32_16x16x32_bf16(whi[g][kc], hfl[kc], a, 0, 0, 0); \
                    a = __builtin_amdgcn_mfma_f32_16x16x32_bf16(wlo[g][kc], hfh[kc], a, 0, 0, 0); \
                }                                                                   \
                ac[g] = a;                                                          \
            }                                                                       \
            _Pragma("unroll")                                                       \
            for (int r = 0; r < 4; ++r) {                                           \
                float iv = ac[0][r] + XV(nt, r, 0);                                 \
                float fv = ac[1][r] + XV(nt, r, 1);                                 \
                float gv = ac[2][r] + XV(nt, r, 2);                                 \
                float ov = ac[3][r] + XV(nt, r, 3);                                 \
                float c = fsigf(fv) * cs[nt][r] + fsigf(iv) * ftanhf(gv);           \
                cs[nt][r] = c;                                                      \
                nh[nt][r] = fsigf(ov) * ftanhf(c);                                  \
            }                                                                       \
        }                                                                           \
        _Pragma("unroll")                                                           \
        for (int nt = 0; nt < 4; ++nt) {                                            \
            unsigned u0 = __float_as_uint(nh[nt][0]);                               \
            unsigned u1 = __float_as_uint(nh[nt][1]);                               \
            unsigned u2 = __float_as_uint(nh[nt][2]);                               \
            unsigned u3 = __float_as_uint(nh[nt][3]);                               \
            unsigned r0 = __float_as_uint(nh[nt][0] - bhi(u0));                     \
            unsigned r1 = __float_as_uint(nh[nt][1] - bhi(u1));                     \
            unsigned r2 = __float_as_uint(nh[nt][2] - bhi(u2));                     \
            unsigned r3 = __float_as_uint(nh[nt][3] - bhi(u3));                     \
            uint2 ph, pl;                                                           \
            ph.x = pkhi(u0, u1); ph.y = pkhi(u2, u3);                               \
            pl.x = pkhi(r0, r1); pl.y = pkhi(r2, r3);                               \
            const int o = (nt * 16 + l15) * 136 + jb + quad * 4;                    \
            *(uint2*)&(wrHi)[o] = ph;                                               \
            *(uint2*)&(wrLo)[o] = pl;                                               \
        }                                                                           \
        __syncthreads();                                                            \
    }

    for (int tp = 0; tp < 8; ++tp) {
        LSTM_STEP(hsAhi, hsAlo, hsBhi, hsBlo, 2 * tp);      // even t: read A write B
        LSTM_STEP(hsBhi, hsBlo, hsAhi, hsAlo, 2 * tp + 1);  // odd  t: read B write A
    }
#undef LSTM_STEP
#undef XV
    // t=15 (odd) wrote A planes -> h_neigh lives in hsA.

    // ---- fused combine: h' = relu(hin@Ws.T + hn@Wn.T + bs + bn) ----
    const int ng = wave & 3, ch = wave >> 2;
    const int nodeA = n0 + ng * 16 + l15;
    const int nclA  = nodeA < NNODES ? nodeA : NNODES - 1;
    short8_t ahh[4], ahl[4], anh[4], anl[4];
#pragma unroll
    for (int kc = 0; kc < 4; ++kc) {
        splitf8(hin + (size_t)nclA * 128 + kc * 32 + quad * 8, ahh[kc], ahl[kc]);
        anh[kc] = *(const short8_t*)&hsAhi[(ng * 16 + l15) * 136 + kc * 32 + quad * 8];
        anl[kc] = *(const short8_t*)&hsAlo[(ng * 16 + l15) * 136 + kc * 32 + quad * 8];
    }
    __syncthreads();   // all hin reads done before any in-place store

#pragma unroll
    for (int ct = 0; ct < 4; ++ct) {
        const int ctg = ch * 4 + ct;
        float4_t acc = (float4_t){0.f, 0.f, 0.f, 0.f};
#pragma unroll
        for (int kc = 0; kc < 4; ++kc) {
            const int kk = kc * 32 + quad * 8;
            short8_t bh, bl;
            splitf8(Ws + (size_t)(ctg * 16 + l15) * 128 + kk, bh, bl);
            acc = __builtin_amdgcn_mfma_f32_16x16x32_bf16(ahh[kc], bh, acc, 0, 0, 0);
            acc = __builtin_amdgcn_mfma_f32_16x16x32_bf16(ahh[kc], bl, acc, 0, 0, 0);
            acc = __builtin_amdgcn_mfma_f32_16x16x32_bf16(ahl[kc], bh, acc, 0, 0, 0);
            splitf8(Wn + (size_t)(ctg * 16 + l15) * 128 + kk, bh, bl);
            acc = __builtin_amdgcn_mfma_f32_16x16x32_bf16(anh[kc], bh, acc, 0, 0, 0);
            acc = __builtin_amdgcn_mfma_f32_16x16x32_bf16(anh[kc], bl, acc, 0, 0, 0);
            acc = __builtin_amdgcn_mfma_f32_16x16x32_bf16(anl[kc], bh, acc, 0, 0, 0);
        }
        const int c = ctg * 16 + l15;
        const float bb = bs[c] + bn[c];
#pragma unroll
        for (int r = 0; r < 4; ++r) {
            int rowo = n0 + ng * 16 + quad * 4 + r;
            if (rowo < NNODES) {
                float v = acc[r] + bb;
                hout[(size_t)rowo * 128 + c] = v > 0.f ? v : 0.f;
            }
        }
    }
}

// ---------------------------------------------------------------------------
// Fused MLP heads (unchanged from R12).
// ---------------------------------------------------------------------------
__global__ __launch_bounds__(256) void heads_fused(
    const float* __restrict__ hsrc,
    const float* __restrict__ clsW, const float* __restrict__ clsb,
    const float* __restrict__ clsoW, const float* __restrict__ clsob,
    const float* __restrict__ cnfW, const float* __restrict__ cnfb,
    const float* __restrict__ cnfoW, const float* __restrict__ cnfob,
    float* __restrict__ oC, float* __restrict__ oL)
{
    __shared__ short xb[64 * 132];    // activations (bf16)
    __shared__ short wb[128 * 132];   // current layer weights (bf16)

    const int tid  = threadIdx.x;
    const int wave = tid >> 6, lane = tid & 63;
    const int l15  = lane & 15, quad = lane >> 4;
    const int n0   = blockIdx.x * 64;

    {
        int row = tid >> 2, cb = (tid & 3) * 32;
        int rsrc = n0 + row; if (rsrc >= NNODES) rsrc = NNODES - 1;
        const float* src = hsrc + (size_t)rsrc * 128 + cb;
#pragma unroll
        for (int i = 0; i < 4; ++i)
            *(short8_t*)&xb[row * 132 + cb + i * 8] = cvtb8(src + i * 8);
    }

    for (int head = 0; head < 2; ++head) {
        const float* W  = head ? cnfW : clsW;
        const float* bv = head ? cnfb : clsb;

        if (head == 1) {
            __syncthreads();
            int row = tid >> 2, cb = (tid & 3) * 32;
            int rsrc = n0 + row; if (rsrc >= NNODES) rsrc = NNODES - 1;
            const float* src = hsrc + (size_t)rsrc * 128 + cb;
#pragma unroll
            for (int i = 0; i < 4; ++i)
                *(short8_t*)&xb[row * 132 + cb + i * 8] = cvtb8(src + i * 8);
        }

        for (int l = 0; l < 5; ++l) {
            __syncthreads();
            short8_t af[4];
#pragma unroll
            for (int kc = 0; kc < 4; ++kc)
                af[kc] = *(const short8_t*)&xb[(wave * 16 + l15) * 132 + kc * 32 + quad * 8];
            const float* Wl = W + (size_t)l * 16384;
#pragma unroll
            for (int i = 0; i < 8; ++i) {
                int e = i * 2048 + tid * 8;
                int r = e >> 7, c = e & 127;
                *(short8_t*)&wb[r * 132 + c] = cvtb8(Wl + e);
            }
            __syncthreads();
#pragma unroll
            for (int ct = 0; ct < 8; ++ct) {
                float4_t acc = (float4_t){0.f, 0.f, 0.f, 0.f};
#pragma unroll
                for (int kc = 0; kc < 4; ++kc) {
                    short8_t bf = *(const short8_t*)&wb[(ct * 16 + l15) * 132 + kc * 32 + quad * 8];
                    acc = __builtin_amdgcn_mfma_f32_16x16x32_bf16(af[kc], bf, acc, 0, 0, 0);
                }
                int c = ct * 16 + l15;
                float bb = bv[l * 128 + c];
#pragma unroll
                for (int r = 0; r < 4; ++r) {
                    float v = acc[r] + bb;
                    v = v > 0.f ? v : 0.f;
                    xb[(wave * 16 + quad * 4 + r) * 132 + c] = (short)f2b(v);
                }
            }
        }

        __syncthreads();
        short8_t af[4];
#pragma unroll
        for (int kc = 0; kc < 4; ++kc)
            af[kc] = *(const short8_t*)&xb[(wave * 16 + l15) * 132 + kc * 32 + quad * 8];
        if (head == 0) {
            int wr = l15 < 10 ? l15 : 9;
            float4_t acc = (float4_t){0.f, 0.f, 0.f, 0.f};
#pragma unroll
            for (int kc = 0; kc < 4; ++kc) {
                short8_t bh, bl;
                splitf8(clsoW + (size_t)wr * 128 + kc * 32 + quad * 8, bh, bl);
                acc = __builtin_amdgcn_mfma_f32_16x16x32_bf16(af[kc], bh, acc, 0, 0, 0);
                acc = __builtin_amdgcn_mfma_f32_16x16x32_bf16(af[kc], bl, acc, 0, 0, 0);
            }
            if (l15 < 10) {
                float bb = clsob[l15];
#pragma unroll
                for (int r = 0; r < 4; ++r) {
                    int row = n0 + wave * 16 + quad * 4 + r;
                    if (row < NNODES) oC[(size_t)row * 10 + l15] = acc[r] + bb;
                }
            }
        } else {
            float4_t acc = (float4_t){0.f, 0.f, 0.f, 0.f};
#pragma unroll
            for (int kc = 0; kc < 4; ++kc) {
                short8_t bh, bl;
                splitf8(cnfoW + kc * 32 + quad * 8, bh, bl);
                acc = __builtin_amdgcn_mfma_f32_16x16x32_bf16(af[kc], bh, acc, 0, 0, 0);
                acc = __builtin_amdgcn_mfma_f32_16x16x32_bf16(af[kc], bl, acc, 0, 0, 0);
            }
            if (l15 == 0) {
                float bb = cnfob[0];
#pragma unroll
                for (int r = 0; r < 4; ++r) {
                    int row = n0 + wave * 16 + quad * 4 + r;
                    if (row < NNODES) oL[row] = acc[r] + bb;
                }
            }
        }
    }
}

// ===========================================================================
extern "C" void kernel_launch(void* const* d_in, const int* in_sizes, int n_in,
                              void* d_out, int out_size, void* d_ws, size_t ws_size,
                              hipStream_t stream)
{
    const float* h0     = (const float*)d_in[0];
    const int*   nbr    = (const int*)d_in[1];
    const float* Wih    = (const float*)d_in[2];   // [2,512,128]
    const float* Whh    = (const float*)d_in[3];   // [2,512,128]
    const float* lb     = (const float*)d_in[4];   // [2,512]
    const float* Wself  = (const float*)d_in[5];   // [2,128,128]
    const float* bself  = (const float*)d_in[6];
    const float* Wneigh = (const float*)d_in[7];
    const float* bneigh = (const float*)d_in[8];
    const float* clsW   = (const float*)d_in[9];   // [5,128,128]
    const float* clsb   = (const float*)d_in[10];
    const float* clsoW  = (const float*)d_in[11];  // [10,128]
    const float* clsob  = (const float*)d_in[12];
    const float* cnfW   = (const float*)d_in[13];
    const float* cnfb   = (const float*)d_in[14];
    const float* cnfoW  = (const float*)d_in[15];  // [1,128]
    const float* cnfob  = (const float*)d_in[16];

    char* ws = (char*)d_ws;
    _Float16* Xhi = (_Float16*)ws;                 // [0, 102.4M)
    char*     Xlo = ws + 102400000;                // [102.4M, 153.6M)

    float* out = (float*)d_out;
    float* oC  = out;                   // [N,10]
    float* hO  = out + 1000000;         // [N,128]; h1/h2 live here
    float* oL  = out + 13800000;        // [N,1]

    dim3 gx(8, 1563);    // xgemm: j-groups fast (A reuse in L2), M=100000
    dim3 gl(1563);       // lstm, 512 thr
    dim3 gf(1563);       // heads_fused, 256 thr

    // ---- layer 1: h1 -> d_out h slot ----
    xgemm_split<<<gx, dim3(256), 0, stream>>>(h0, Wih, lb, Xhi, Xlo);
    lstm_comb<<<gl, dim3(512), 0, stream>>>(Xhi, Xlo, nbr, Whh, h0,
                                            Wself, Wneigh, bself, bneigh, hO);
    // ---- layer 2: h2 -> same slot, in-place ----
    xgemm_split<<<gx, dim3(256), 0, stream>>>(hO, Wih + 65536, lb + 512, Xhi, Xlo);
    lstm_comb<<<gl, dim3(512), 0, stream>>>(Xhi, Xlo, nbr, Whh + 65536, hO,
                                            Wself + 16384, Wneigh + 16384,
                                            bself + 128, bneigh + 128, hO);

    // ---- heads: one fused dispatch ----
    heads_fused<<<gf, dim3(256), 0, stream>>>(hO, clsW, clsb, clsoW, clsob,
                                              cnfW, cnfb, cnfoW, cnfob, oC, oL);
}

// Round 13
// 2716.619 us; speedup vs baseline: 1.5067x; 1.0108x over previous
//
#include <hip/hip_runtime.h>
#include <stdint.h>

// GNNCell: 2x SAGEConv(lstm) + 2 MLP heads. N=100000, D=16, H=128, fp32 I/O.
// R19 passed 2746 us (lstm 2x~1137 WRITE 72MB frozen; gate-major xgemm
//     writes coalesced). lstm_comb CLOSED: 5 perturbations all spilled.
// R20: kill repeated weight conversion outside lstm (zero lstm risk):
//     (1) Wih pre-split to bf16 hi/lo planes ONCE (was 16 splitf8_pk/thread
//         x 12504 blocks on the same 256KB matrix) -> xgemm B = pure loads.
//     (2) clsW/cnfW pre-converted to bf16 ONCE -> heads_fused staging is
//         load->store (was 32 cvtpk/thread/layer), load bytes halved.
//     (3) heads_fused snapshots the bf16 h-tile in LDS (xb0) at entry;
//         head 1 restores via LDS copy instead of global re-read + cvt.
//     Conversions use the SAME splitf8_pk/cvtb8 -> bit-identical absmax.
// Workspace: X 153.6MB + weight caches ~0.9MB < 204.8MB (proven available,
//     R13 fast path ran).
// Precision: X fp16-hi + i8-lo(2^-15); recurrence split-bf16 3-MFMA with
// truncated-hi hs (lo-compensated); heads bf16.

typedef __attribute__((ext_vector_type(8))) short short8_t;
typedef __attribute__((ext_vector_type(4))) float float4_t;
typedef __attribute__((ext_vector_type(4))) unsigned uint4_t;
typedef _Float16 half8_t __attribute__((ext_vector_type(8)));

#define NNODES 100000
#define DNB 16
#define LOSCALE 32768.0f
#define LOINV   3.0517578125e-5f   // 2^-15

__device__ __forceinline__ float fsigf(float x) {
    return __builtin_amdgcn_rcpf(1.f + __expf(-x));
}
__device__ __forceinline__ float ftanhf(float x) {
    return 1.f - 2.f * __builtin_amdgcn_rcpf(1.f + __expf(2.f * x));
}
__device__ __forceinline__ unsigned f2b(float f) {  // RNE f32->bf16 (finite)
    unsigned u = __float_as_uint(f);
    return (u + 0x7FFFu + ((u >> 16) & 1u)) >> 16;
}
__device__ __forceinline__ float blo(unsigned u) { return __uint_as_float(u << 16); }
__device__ __forceinline__ float bhi(unsigned u) { return __uint_as_float(u & 0xFFFF0000u); }
// pack hi16(u0) | hi16(u1)<<16 in ONE v_perm_b32 (builtin -> no reg pinning)
__device__ __forceinline__ unsigned pkhi(unsigned u0, unsigned u1) {
    return __builtin_amdgcn_perm(u1, u0, 0x07060302u);
}
// f2b-based split: compiler-friendly (values can migrate to AGPRs).
__device__ __forceinline__ void splitf8(const float* __restrict__ p, short8_t& hi, short8_t& lo) {
    float4_t a = *(const float4_t*)p;
    float4_t b = *(const float4_t*)(p + 4);
#pragma unroll
    for (int j = 0; j < 8; ++j) {
        float x = j < 4 ? a[j] : b[j - 4];
        unsigned hb = f2b(x);
        float hf = __uint_as_float(hb << 16);
        unsigned lb = f2b(x - hf);
        hi[j] = (short)hb;
        lo[j] = (short)lb;
    }
}
// packed f32 pair -> 2x bf16 (inline asm: ONLY transient values in
// low-pressure kernels; never in lstm_comb).
__device__ __forceinline__ unsigned cvtpk(float lo, float hi) {
    unsigned r;
    asm("v_cvt_pk_bf16_f32 %0, %1, %2" : "=v"(r) : "v"(lo), "v"(hi));
    return r;
}
__device__ __forceinline__ void splitf8_pk(const float* __restrict__ p, short8_t& hi, short8_t& lo) {
    float4_t a = *(const float4_t*)p;
    float4_t b = *(const float4_t*)(p + 4);
    unsigned h0 = cvtpk(a[0], a[1]), h1 = cvtpk(a[2], a[3]);
    unsigned h2 = cvtpk(b[0], b[1]), h3 = cvtpk(b[2], b[3]);
    unsigned l0 = cvtpk(a[0] - blo(h0), a[1] - bhi(h0));
    unsigned l1 = cvtpk(a[2] - blo(h1), a[3] - bhi(h1));
    unsigned l2 = cvtpk(b[0] - blo(h2), b[1] - bhi(h2));
    unsigned l3 = cvtpk(b[2] - blo(h3), b[3] - bhi(h3));
    union { uint4_t u; short8_t s; } ch, cl;
    ch.u = (uint4_t){h0, h1, h2, h3};
    cl.u = (uint4_t){l0, l1, l2, l3};
    hi = ch.s;
    lo = cl.s;
}
// fp32[8] -> bf16x8 (plain cast, head path)
__device__ __forceinline__ short8_t cvtb8(const float* __restrict__ p) {
    float4_t a = *(const float4_t*)p;
    float4_t b = *(const float4_t*)(p + 4);
    union { uint4_t u; short8_t s; } c;
    c.u = (uint4_t){cvtpk(a[0], a[1]), cvtpk(a[2], a[3]),
                    cvtpk(b[0], b[1]), cvtpk(b[2], b[3])};
    return c.s;
}

// ---------------------------------------------------------------------------
// One-shot weight conversion kernels (run once per launch, ~10us total).
// ---------------------------------------------------------------------------
__global__ __launch_bounds__(256) void cvt_split(
    const float* __restrict__ W, short* __restrict__ H, short* __restrict__ L, int n8)
{
    int idx = blockIdx.x * 256 + threadIdx.x;
    if (idx >= n8) return;
    short8_t hi, lo;
    splitf8_pk(W + (size_t)idx * 8, hi, lo);
    *(short8_t*)&H[(size_t)idx * 8] = hi;
    *(short8_t*)&L[(size_t)idx * 8] = lo;
}
__global__ __launch_bounds__(256) void cvt_b16(
    const float* __restrict__ W, short* __restrict__ O, int n8)
{
    int idx = blockIdx.x * 256 + threadIdx.x;
    if (idx >= n8) return;
    *(short8_t*)&O[(size_t)idx * 8] = cvtb8(W + (size_t)idx * 8);
}

// ---------------------------------------------------------------------------
// X = h @ Wih.T + b, split-bf16 3-MFMA (rel ~2^-16), stored fp16-hi + i8-lo.
// GATE-MAJOR tiling (R19): block covers j-group j0=bx*16 across ALL 4 gates.
// B operand from PRE-SPLIT bf16 hi/lo planes (pure 16B loads, no cvt).
// Layout (reader side) unchanged: element c=g*128+j at node*512 + j*4 + g.
// ---------------------------------------------------------------------------
__global__ __launch_bounds__(256) void xgemm_split(
    const float* __restrict__ A, const short* __restrict__ BH,
    const short* __restrict__ BL, const float* __restrict__ bias,
    _Float16* __restrict__ Chi, char* __restrict__ Clo)
{
    const int tid  = threadIdx.x;
    const int wave = tid >> 6, lane = tid & 63;
    const int l15  = lane & 15, quad = lane >> 4;
    const int r0   = blockIdx.y * 64 + wave * 16;
    const int j0   = blockIdx.x * 16;

    int arow = r0 + l15;
    if (arow >= NNODES) arow = NNODES - 1;

    float4_t acc[4];   // acc[g]
#pragma unroll
    for (int g = 0; g < 4; ++g) acc[g] = (float4_t){0.f, 0.f, 0.f, 0.f};

#pragma unroll
    for (int kc = 0; kc < 4; ++kc) {
        const int kk = kc * 32 + quad * 8;
        short8_t ah, al;
        splitf8_pk(A + (size_t)arow * 128 + kk, ah, al);
#pragma unroll
        for (int g = 0; g < 4; ++g) {
            const size_t bo = (size_t)(g * 128 + j0 + l15) * 128 + kk;
            short8_t bh = *(const short8_t*)&BH[bo];
            short8_t bl = *(const short8_t*)&BL[bo];
            acc[g] = __builtin_amdgcn_mfma_f32_16x16x32_bf16(ah, bh, acc[g], 0, 0, 0);
            acc[g] = __builtin_amdgcn_mfma_f32_16x16x32_bf16(ah, bl, acc[g], 0, 0, 0);
            acc[g] = __builtin_amdgcn_mfma_f32_16x16x32_bf16(al, bh, acc[g], 0, 0, 0);
        }
    }

    float bb[4];
#pragma unroll
    for (int g = 0; g < 4; ++g) bb[g] = bias[g * 128 + j0 + l15];

#pragma unroll
    for (int r = 0; r < 4; ++r) {
        int rowo = r0 + quad * 4 + r;
        if (rowo < NNODES) {
            union { uint2 u; _Float16 h[4]; } P;
            unsigned pl = 0;
#pragma unroll
            for (int g = 0; g < 4; ++g) {
                float v = acc[g][r] + bb[g];
                _Float16 hi = (_Float16)v;
                float res = v - (float)hi;
                int q = (int)rintf(res * LOSCALE);
                q = q > 127 ? 127 : (q < -127 ? -127 : q);
                P.h[g] = hi;
                pl |= ((unsigned)q & 0xFFu) << (g * 8);
            }
            *(uint2*)&Chi[(size_t)rowo * 512 + (j0 + l15) * 4] = P.u;
            *(unsigned*)&Clo[(size_t)rowo * 512 + (j0 + l15) * 4] = pl;
        }
    }
}

// ---------------------------------------------------------------------------
// Fused 16-step LSTM + combine — R14 BYTE-IDENTICAL (proven no-spill).
// FROZEN: any change to this kernel's register allocation spills (5x).
// ---------------------------------------------------------------------------
__global__ __launch_bounds__(512, 2) void lstm_comb(
    const _Float16* __restrict__ Xhi, const char* __restrict__ Xlo,
    const int* __restrict__ nbr, const float* __restrict__ Whh,
    const float* hin, const float* __restrict__ Ws,
    const float* __restrict__ Wn, const float* __restrict__ bs,
    const float* __restrict__ bn, float* hout)
{
    __shared__ short hsAhi[64 * 136], hsAlo[64 * 136];
    __shared__ short hsBhi[64 * 136], hsBlo[64 * 136];
    __shared__ int   nbrs[64 * 17];

    const int tid  = threadIdx.x;
    const int wave = tid >> 6, lane = tid & 63;
    const int l15  = lane & 15, quad = lane >> 4;
    const int n0   = blockIdx.x * 64;
    const int jb   = wave * 16;
    const int xoff = jb * 4 + quad * 16;   // gate-interleaved lane offset

    for (int i = tid; i < 64 * 136 / 2; i += 512) {
        ((unsigned*)hsAhi)[i] = 0;
        ((unsigned*)hsAlo)[i] = 0;
    }
    for (int i = tid; i < 64 * DNB; i += 512) {
        int node = n0 + (i >> 4);
        if (node >= NNODES) node = NNODES - 1;
        nbrs[(i >> 4) * 17 + (i & 15)] = nbr[node * DNB + (i & 15)];
    }

    // Whh split fragments: 4 gates x 4 k-chunks x (hi,lo) = 32 frags
    short8_t whi[4][4], wlo[4][4];
#pragma unroll
    for (int g = 0; g < 4; ++g)
#pragma unroll
        for (int kc = 0; kc < 4; ++kc)
            splitf8(Whh + (size_t)(g * 128 + jb + l15) * 128 + kc * 32 + quad * 8,
                    whi[g][kc], wlo[g][kc]);

    float cs[4][4], nh[4][4];
#pragma unroll
    for (int a = 0; a < 4; ++a)
#pragma unroll
        for (int b = 0; b < 4; ++b) { cs[a][b] = 0.f; nh[a][b] = 0.f; }

    __syncthreads();

// hi value (g,r) lives at vector slot r*4+g; lo byte g of word r.
#define XV(nt, r, g)                                                                \
    ((float)(((r) * 4 + (g)) < 8 ? xh0[nt][(r) * 4 + (g)] : xh1[nt][(r) * 4 + (g) - 8]) \
     + (float)((signed char)(xl4[nt][(r)] >> ((g) * 8))) * LOINV)

#define LSTM_STEP(rdHi, rdLo, wrHi, wrLo, T)                                        \
    {                                                                               \
        half8_t xh0[4], xh1[4]; uint4_t xl4[4];                                     \
        _Pragma("unroll")                                                           \
        for (int nt = 0; nt < 4; ++nt) {                                            \
            int gi = nbrs[(nt * 16 + l15) * 17 + (T)];                              \
            size_t xb = (size_t)gi * 512 + xoff;                                    \
            xh0[nt] = *(const half8_t*)(Xhi + xb);                                  \
            xh1[nt] = *(const half8_t*)(Xhi + xb + 8);                              \
            xl4[nt] = *(const uint4_t*)(Xlo + xb);                                  \
        }                                                                           \
        _Pragma("unroll")                                                           \
        for (int nt = 0; nt < 4; ++nt) {                                            \
            short8_t hfh[4], hfl[4];                                                \
            _Pragma("unroll")                                                       \
            for (int kc = 0; kc < 4; ++kc) {                                        \
                hfh[kc] = *(const short8_t*)&(rdHi)[(nt * 16 + l15) * 136 + kc * 32 + quad * 8]; \
                hfl[kc] = *(const short8_t*)&(rdLo)[(nt * 16 + l15) * 136 + kc * 32 + quad * 8]; \
            }                                                                       \
            float4_t ac[4];                                                         \
            _Pragma("unroll")                                                       \
            for (int g = 0; g < 4; ++g) {                                           \
                float4_t a = (float4_t){0.f, 0.f, 0.f, 0.f};                        \
                _Pragma("unroll")                                                   \
                for (int kc = 0; kc < 4; ++kc) {                                    \
                    a = __builtin_amdgcn_mfma_f32_16x16x32_bf16(whi[g][kc], hfh[kc], a, 0, 0, 0); \
                    a = __builtin_amdgcn_mfma_f32_16x16x32_bf16(whi[g][kc], hfl[kc], a, 0, 0, 0); \
                    a = __builtin_amdgcn_mfma_f32_16x16x32_bf16(wlo[g][kc], hfh[kc], a, 0, 0, 0); \
                }                                                                   \
                ac[g] = a;                                                          \
            }                                                                       \
            _Pragma("unroll")                                                       \
            for (int r = 0; r < 4; ++r) {                                           \
                float iv = ac[0][r] + XV(nt, r, 0);                                 \
                float fv = ac[1][r] + XV(nt, r, 1);                                 \
                float gv = ac[2][r] + XV(nt, r, 2);                                 \
                float ov = ac[3][r] + XV(nt, r, 3);                                 \
                float c = fsigf(fv) * cs[nt][r] + fsigf(iv) * ftanhf(gv);           \
                cs[nt][r] = c;                                                      \
                nh[nt][r] = fsigf(ov) * ftanhf(c);                                  \
            }                                                                       \
        }                                                                           \
        _Pragma("unroll")                                                           \
        for (int nt = 0; nt < 4; ++nt) {                                            \
            unsigned u0 = __float_as_uint(nh[nt][0]);                               \
            unsigned u1 = __float_as_uint(nh[nt][1]);                               \
            unsigned u2 = __float_as_uint(nh[nt][2]);                               \
            unsigned u3 = __float_as_uint(nh[nt][3]);                               \
            unsigned r0 = __float_as_uint(nh[nt][0] - bhi(u0));                     \
            unsigned r1 = __float_as_uint(nh[nt][1] - bhi(u1));                     \
            unsigned r2 = __float_as_uint(nh[nt][2] - bhi(u2));                     \
            unsigned r3 = __float_as_uint(nh[nt][3] - bhi(u3));                     \
            uint2 ph, pl;                                                           \
            ph.x = pkhi(u0, u1); ph.y = pkhi(u2, u3);                               \
            pl.x = pkhi(r0, r1); pl.y = pkhi(r2, r3);                               \
            const int o = (nt * 16 + l15) * 136 + jb + quad * 4;                    \
            *(uint2*)&(wrHi)[o] = ph;                                               \
            *(uint2*)&(wrLo)[o] = pl;                                               \
        }                                                                           \
        __syncthreads();                                                            \
    }

    for (int tp = 0; tp < 8; ++tp) {
        LSTM_STEP(hsAhi, hsAlo, hsBhi, hsBlo, 2 * tp);      // even t: read A write B
        LSTM_STEP(hsBhi, hsBlo, hsAhi, hsAlo, 2 * tp + 1);  // odd  t: read B write A
    }
#undef LSTM_STEP
#undef XV
    // t=15 (odd) wrote A planes -> h_neigh lives in hsA.

    // ---- fused combine: h' = relu(hin@Ws.T + hn@Wn.T + bs + bn) ----
    const int ng = wave & 3, ch = wave >> 2;
    const int nodeA = n0 + ng * 16 + l15;
    const int nclA  = nodeA < NNODES ? nodeA : NNODES - 1;
    short8_t ahh[4], ahl[4], anh[4], anl[4];
#pragma unroll
    for (int kc = 0; kc < 4; ++kc) {
        splitf8(hin + (size_t)nclA * 128 + kc * 32 + quad * 8, ahh[kc], ahl[kc]);
        anh[kc] = *(const short8_t*)&hsAhi[(ng * 16 + l15) * 136 + kc * 32 + quad * 8];
        anl[kc] = *(const short8_t*)&hsAlo[(ng * 16 + l15) * 136 + kc * 32 + quad * 8];
    }
    __syncthreads();   // all hin reads done before any in-place store

#pragma unroll
    for (int ct = 0; ct < 4; ++ct) {
        const int ctg = ch * 4 + ct;
        float4_t acc = (float4_t){0.f, 0.f, 0.f, 0.f};
#pragma unroll
        for (int kc = 0; kc < 4; ++kc) {
            const int kk = kc * 32 + quad * 8;
            short8_t bh, bl;
            splitf8(Ws + (size_t)(ctg * 16 + l15) * 128 + kk, bh, bl);
            acc = __builtin_amdgcn_mfma_f32_16x16x32_bf16(ahh[kc], bh, acc, 0, 0, 0);
            acc = __builtin_amdgcn_mfma_f32_16x16x32_bf16(ahh[kc], bl, acc, 0, 0, 0);
            acc = __builtin_amdgcn_mfma_f32_16x16x32_bf16(ahl[kc], bh, acc, 0, 0, 0);
            splitf8(Wn + (size_t)(ctg * 16 + l15) * 128 + kk, bh, bl);
            acc = __builtin_amdgcn_mfma_f32_16x16x32_bf16(anh[kc], bh, acc, 0, 0, 0);
            acc = __builtin_amdgcn_mfma_f32_16x16x32_bf16(anh[kc], bl, acc, 0, 0, 0);
            acc = __builtin_amdgcn_mfma_f32_16x16x32_bf16(anl[kc], bh, acc, 0, 0, 0);
        }
        const int c = ctg * 16 + l15;
        const float bb = bs[c] + bn[c];
#pragma unroll
        for (int r = 0; r < 4; ++r) {
            int rowo = n0 + ng * 16 + quad * 4 + r;
            if (rowo < NNODES) {
                float v = acc[r] + bb;
                hout[(size_t)rowo * 128 + c] = v > 0.f ? v : 0.f;
            }
        }
    }
}

// ---------------------------------------------------------------------------
// Fused MLP heads. Weights from PRE-CONVERTED bf16 (pure load->LDS staging);
// h tile snapshotted in xb0 at entry, head 1 restores via LDS copy.
// ---------------------------------------------------------------------------
__global__ __launch_bounds__(256) void heads_fused(
    const float* __restrict__ hsrc,
    const short* __restrict__ clsW16, const float* __restrict__ clsb,
    const float* __restrict__ clsoW, const float* __restrict__ clsob,
    const short* __restrict__ cnfW16, const float* __restrict__ cnfb,
    const float* __restrict__ cnfoW, const float* __restrict__ cnfob,
    float* __restrict__ oC, float* __restrict__ oL)
{
    __shared__ short xb[64 * 132];    // activations (bf16)
    __shared__ short xb0[64 * 132];   // h-tile snapshot for head 1
    __shared__ short wb[128 * 132];   // current layer weights (bf16)

    const int tid  = threadIdx.x;
    const int wave = tid >> 6, lane = tid & 63;
    const int l15  = lane & 15, quad = lane >> 4;
    const int n0   = blockIdx.x * 64;

    {
        int row = tid >> 2, cb = (tid & 3) * 32;
        int rsrc = n0 + row; if (rsrc >= NNODES) rsrc = NNODES - 1;
        const float* src = hsrc + (size_t)rsrc * 128 + cb;
#pragma unroll
        for (int i = 0; i < 4; ++i) {
            short8_t v = cvtb8(src + i * 8);
            *(short8_t*)&xb[row * 132 + cb + i * 8]  = v;
            *(short8_t*)&xb0[row * 132 + cb + i * 8] = v;
        }
    }

    for (int head = 0; head < 2; ++head) {
        const short* W16 = head ? cnfW16 : clsW16;
        const float* bv  = head ? cnfb : clsb;

        if (head == 1) {
            __syncthreads();   // cls-final xb reads complete
            for (int i = tid; i < 64 * 132 / 2; i += 256)
                ((unsigned*)xb)[i] = ((const unsigned*)xb0)[i];
        }

        for (int l = 0; l < 5; ++l) {
            __syncthreads();   // xb writes visible; prev wb consumers done
            short8_t af[4];
#pragma unroll
            for (int kc = 0; kc < 4; ++kc)
                af[kc] = *(const short8_t*)&xb[(wave * 16 + l15) * 132 + kc * 32 + quad * 8];
            const short* Wl = W16 + (size_t)l * 16384;
#pragma unroll
            for (int i = 0; i < 8; ++i) {
                int e = i * 2048 + tid * 8;
                int r = e >> 7, c = e & 127;
                *(short8_t*)&wb[r * 132 + c] = *(const short8_t*)&Wl[e];
            }
            __syncthreads();   // wb ready; all af reads done
#pragma unroll
            for (int ct = 0; ct < 8; ++ct) {
                float4_t acc = (float4_t){0.f, 0.f, 0.f, 0.f};
#pragma unroll
                for (int kc = 0; kc < 4; ++kc) {
                    short8_t bf = *(const short8_t*)&wb[(ct * 16 + l15) * 132 + kc * 32 + quad * 8];
                    acc = __builtin_amdgcn_mfma_f32_16x16x32_bf16(af[kc], bf, acc, 0, 0, 0);
                }
                int c = ct * 16 + l15;
                float bb = bv[l * 128 + c];
#pragma unroll
                for (int r = 0; r < 4; ++r) {
                    float v = acc[r] + bb;
                    v = v > 0.f ? v : 0.f;
                    xb[(wave * 16 + quad * 4 + r) * 132 + c] = (short)f2b(v);
                }
            }
        }

        // ---- final linear (no relu), compensated split-bf16 oW ----
        __syncthreads();   // last layer xb visible
        short8_t af[4];
#pragma unroll
        for (int kc = 0; kc < 4; ++kc)
            af[kc] = *(const short8_t*)&xb[(wave * 16 + l15) * 132 + kc * 32 + quad * 8];
        if (head == 0) {
            int wr = l15 < 10 ? l15 : 9;
            float4_t acc = (float4_t){0.f, 0.f, 0.f, 0.f};
#pragma unroll
            for (int kc = 0; kc < 4; ++kc) {
                short8_t bh, bl;
                splitf8(clsoW + (size_t)wr * 128 + kc * 32 + quad * 8, bh, bl);
                acc = __builtin_amdgcn_mfma_f32_16x16x32_bf16(af[kc], bh, acc, 0, 0, 0);
                acc = __builtin_amdgcn_mfma_f32_16x16x32_bf16(af[kc], bl, acc, 0, 0, 0);
            }
            if (l15 < 10) {
                float bb = clsob[l15];
#pragma unroll
                for (int r = 0; r < 4; ++r) {
                    int row = n0 + wave * 16 + quad * 4 + r;
                    if (row < NNODES) oC[(size_t)row * 10 + l15] = acc[r] + bb;
                }
            }
        } else {
            float4_t acc = (float4_t){0.f, 0.f, 0.f, 0.f};
#pragma unroll
            for (int kc = 0; kc < 4; ++kc) {
                short8_t bh, bl;
                splitf8(cnfoW + kc * 32 + quad * 8, bh, bl);
                acc = __builtin_amdgcn_mfma_f32_16x16x32_bf16(af[kc], bh, acc, 0, 0, 0);
                acc = __builtin_amdgcn_mfma_f32_16x16x32_bf16(af[kc], bl, acc, 0, 0, 0);
            }
            if (l15 == 0) {
                float bb = cnfob[0];
#pragma unroll
                for (int r = 0; r < 4; ++r) {
                    int row = n0 + wave * 16 + quad * 4 + r;
                    if (row < NNODES) oL[row] = acc[r] + bb;
                }
            }
        }
    }
}

// ===========================================================================
extern "C" void kernel_launch(void* const* d_in, const int* in_sizes, int n_in,
                              void* d_out, int out_size, void* d_ws, size_t ws_size,
                              hipStream_t stream)
{
    const float* h0     = (const float*)d_in[0];
    const int*   nbr    = (const int*)d_in[1];
    const float* Wih    = (const float*)d_in[2];   // [2,512,128]
    const float* Whh    = (const float*)d_in[3];   // [2,512,128]
    const float* lb     = (const float*)d_in[4];   // [2,512]
    const float* Wself  = (const float*)d_in[5];   // [2,128,128]
    const float* bself  = (const float*)d_in[6];
    const float* Wneigh = (const float*)d_in[7];
    const float* bneigh = (const float*)d_in[8];
    const float* clsW   = (const float*)d_in[9];   // [5,128,128]
    const float* clsb   = (const float*)d_in[10];
    const float* clsoW  = (const float*)d_in[11];  // [10,128]
    const float* clsob  = (const float*)d_in[12];
    const float* cnfW   = (const float*)d_in[13];
    const float* cnfb   = (const float*)d_in[14];
    const float* cnfoW  = (const float*)d_in[15];  // [1,128]
    const float* cnfob  = (const float*)d_in[16];

    char* ws = (char*)d_ws;
    _Float16* Xhi = (_Float16*)ws;                 // [0, 102.4M)
    char*     Xlo = ws + 102400000;                // [102.4M, 153.6M)
    short* WihH   = (short*)(ws + 153600000);      // 2x65536 shorts = 256KB
    short* WihL   = (short*)(ws + 153862144);
    short* clsW16 = (short*)(ws + 154124288);      // 81920 shorts = 160KB
    short* cnfW16 = (short*)(ws + 154288128);      // (end ~154.45M < 204.8M)

    float* out = (float*)d_out;
    float* oC  = out;                   // [N,10]
    float* hO  = out + 1000000;         // [N,128]; h1/h2 live here
    float* oL  = out + 13800000;        // [N,1]

    dim3 gx(8, 1563);    // xgemm: j-groups fast, M=100000
    dim3 gl(1563);       // lstm, 512 thr
    dim3 gf(1563);       // heads_fused, 256 thr

    // ---- one-shot weight conversion (~10us) ----
    cvt_split<<<dim3(64), dim3(256), 0, stream>>>(Wih, WihH, WihL, 16384);
    cvt_b16<<<dim3(40), dim3(256), 0, stream>>>(clsW, clsW16, 10240);
    cvt_b16<<<dim3(40), dim3(256), 0, stream>>>(cnfW, cnfW16, 10240);

    // ---- layer 1: h1 -> d_out h slot ----
    xgemm_split<<<gx, dim3(256), 0, stream>>>(h0, WihH, WihL, lb, Xhi, Xlo);
    lstm_comb<<<gl, dim3(512), 0, stream>>>(Xhi, Xlo, nbr, Whh, h0,
                                            Wself, Wneigh, bself, bneigh, hO);
    // ---- layer 2: h2 -> same slot, in-place ----
    xgemm_split<<<gx, dim3(256), 0, stream>>>(hO, WihH + 65536, WihL + 65536,
                                              lb + 512, Xhi, Xlo);
    lstm_comb<<<gl, dim3(512), 0, stream>>>(Xhi, Xlo, nbr, Whh + 65536, hO,
                                            Wself + 16384, Wneigh + 16384,
                                            bself + 128, bneigh + 128, hO);

    // ---- heads: one fused dispatch ----
    heads_fused<<<gf, dim3(256), 0, stream>>>(hO, clsW16, clsb, clsoW, clsob,
                                              cnfW16, cnfb, cnfoW, cnfob, oC, oL);
}